// Round 5
// baseline (371.054 us; speedup 1.0000x reference)
//
#include <hip/hip_runtime.h>
#include <math.h>

#define NN 50000
#define EE 800000

typedef __attribute__((ext_vector_type(8))) short bf16x8;
typedef __attribute__((ext_vector_type(4))) float f32x4;

__device__ __forceinline__ unsigned short f2bf(float f) {
  union { float f; unsigned u; } z; z.f = f;
  return (unsigned short)((z.u + 0x7fffu + ((z.u >> 16) & 1u)) >> 16);
}
__device__ __forceinline__ float bf2f(unsigned int h16) {
  union { unsigned u; float f; } z; z.u = h16 << 16; return z.f;
}
__device__ __forceinline__ float uasf(unsigned u) {
  union { unsigned u; float f; } z; z.u = u; return z.f;
}
__device__ __forceinline__ unsigned cvtpk(float lo, float hi) {
  unsigned r;
  asm("v_cvt_pk_bf16_f32 %0, %1, %2" : "=v"(r) : "v"(lo), "v"(hi));
  return r;
}
__device__ __forceinline__ float sigm(float v) { return 1.0f / (1.0f + __expf(-v)); }

__device__ __forceinline__ bf16x8 pack8(float a0, float a1, float a2, float a3,
                                        float a4, float a5, float a6, float a7) {
  bf16x8 r;
  r[0] = (short)f2bf(a0); r[1] = (short)f2bf(a1);
  r[2] = (short)f2bf(a2); r[3] = (short)f2bf(a3);
  r[4] = (short)f2bf(a4); r[5] = (short)f2bf(a5);
  r[6] = (short)f2bf(a6); r[7] = (short)f2bf(a7);
  return r;
}

// ============ K0: pack all weights into bf16 MFMA A-fragments ============
__global__ __launch_bounds__(64) void k0_prep(const float* __restrict__ W1,
                                              const float* __restrict__ W2,
                                              const float* __restrict__ Wih,
                                              const float* __restrict__ Whh,
                                              unsigned short* __restrict__ frags) {
  const int f = blockIdx.x, l = threadIdx.x;
  const int c16 = l & 15, kg = l >> 4;
  float v[8];
  if (f < 8) {
    const int c = f * 16 + c16;
#pragma unroll
    for (int j = 0; j < 8; ++j) {
      const int k = kg * 8 + j;
      v[j] = (k < 20) ? W1[(256 + k) * 128 + c] : 0.0f;
    }
  } else if (f < 40) {
    const int lf = f - 8, ct = lf >> 2, ks = lf & 3, c = ct * 16 + c16;
#pragma unroll
    for (int j = 0; j < 8; ++j) { const int k = ks * 32 + kg * 8 + j; v[j] = W2[k * 128 + c]; }
  } else if (f < 104) {
    const int lf = f - 40, ct = lf >> 2, ks = lf & 3, c = ct * 16 + c16;
#pragma unroll
    for (int j = 0; j < 8; ++j) {
      const int k = ks * 32 + kg * 8 + j;
      v[j] = (c < 128) ? W1[k * 128 + c] : W1[(128 + k) * 128 + (c - 128)];
    }
  } else if (f < 200) {
    const int lf = f - 104, ct = lf >> 2, ks = lf & 3, c = ct * 16 + c16;
#pragma unroll
    for (int j = 0; j < 8; ++j) { const int k = ks * 32 + kg * 8 + j; v[j] = Wih[c * 128 + k]; }
  } else {
    const int lf = f - 200, ct = lf >> 2, ks = lf & 3, c = ct * 16 + c16;
#pragma unroll
    for (int j = 0; j < 8; ++j) { const int k = ks * 32 + kg * 8 + j; v[j] = Whh[c * 128 + k]; }
  }
  *(bf16x8*)(frags + (size_t)f * 512 + l * 8) =
      pack8(v[0], v[1], v[2], v[3], v[4], v[5], v[6], v[7]);
}

// ============ counting sort of edges by dst ============
__global__ __launch_bounds__(256) void k_hist(const int* __restrict__ ei,
                                              int* __restrict__ deg) {
  const int e = blockIdx.x * 256 + threadIdx.x;
  if (e < EE) atomicAdd(&deg[ei[EE + e]], 1);
}

__global__ __launch_bounds__(256) void kA_partial(const int* __restrict__ deg,
                                                  int* __restrict__ bsum) {
  const int i = blockIdx.x * 256 + threadIdx.x;
  int v = (i < NN) ? deg[i] : 0;
#pragma unroll
  for (int o = 32; o > 0; o >>= 1) v += __shfl_down(v, o);
  __shared__ int wsum[4];
  if ((threadIdx.x & 63) == 0) wsum[threadIdx.x >> 6] = v;
  __syncthreads();
  if (threadIdx.x == 0) bsum[blockIdx.x] = wsum[0] + wsum[1] + wsum[2] + wsum[3];
}

__global__ __launch_bounds__(256) void kB_scan(const int* __restrict__ bsum,
                                               int* __restrict__ boff) {
  __shared__ int s[256];
  const int t = threadIdx.x;
  const int orig = (t < 196) ? bsum[t] : 0;
  s[t] = orig;
  __syncthreads();
  for (int o = 1; o < 256; o <<= 1) {
    const int v = (t >= o) ? s[t - o] : 0;
    __syncthreads();
    s[t] += v;
    __syncthreads();
  }
  if (t < 196) boff[t] = s[t] - orig;
}

__global__ __launch_bounds__(256) void kC_offs(const int* __restrict__ deg,
                                               const int* __restrict__ boff,
                                               int* __restrict__ offs) {
  __shared__ int s[256];
  const int t = threadIdx.x, i = blockIdx.x * 256 + t;
  const int orig = (i < NN) ? deg[i] : 0;
  s[t] = orig;
  __syncthreads();
  for (int o = 1; o < 256; o <<= 1) {
    const int v = (t >= o) ? s[t - o] : 0;
    __syncthreads();
    s[t] += v;
    __syncthreads();
  }
  if (i < NN) offs[i] = boff[blockIdx.x] + s[t] - orig;
}

__global__ __launch_bounds__(256) void k_scatter(const int* __restrict__ ei,
                                                 const int* __restrict__ offs,
                                                 int* __restrict__ cur,
                                                 int* __restrict__ perm) {
  const int e = blockIdx.x * 256 + threadIdx.x;
  if (e < EE) {
    const int d = ei[EE + e];
    const int p = atomicAdd(&cur[d], 1);
    perm[offs[d] + p] = e;
  }
}

// ============ K1: P[n][0:256] = x @ [W1_dst | W1_src]  (bf16 out) ============
__global__ __launch_bounds__(256) void k1_node_pre(const float* __restrict__ x,
                                                   const unsigned short* __restrict__ W1nf,
                                                   unsigned short* __restrict__ P) {
  const int t = threadIdx.x, lane = t & 63, w = t >> 6;
  const int kg = lane >> 4, li = lane & 15;
  const int node = blockIdx.x * 16 + li;   // 3125*16 = 50000 exact
  const f32x4 zf = {0.0f, 0.0f, 0.0f, 0.0f};
  f32x4 acc[4] = {zf, zf, zf, zf};
#pragma unroll
  for (int ks = 0; ks < 4; ++ks) {
    const float* xp = x + (size_t)node * 128 + ks * 32 + kg * 8;
    const float4 u = *(const float4*)xp, v = *(const float4*)(xp + 4);
    const bf16x8 xb = pack8(u.x, u.y, u.z, u.w, v.x, v.y, v.z, v.w);
#pragma unroll
    for (int i = 0; i < 4; ++i) {
      const int ct = w * 4 + i;
      const bf16x8 af = *(const bf16x8*)(W1nf + (size_t)(ct * 4 + ks) * 512 + lane * 8);
      acc[i] = __builtin_amdgcn_mfma_f32_16x16x32_bf16(af, xb, acc[i], 0, 0, 0);
    }
  }
#pragma unroll
  for (int i = 0; i < 4; ++i) {
    const int c0 = (w * 4 + i) * 16 + kg * 4;
    const unsigned lo = cvtpk(acc[i][0], acc[i][1]);
    const unsigned hi = cvtpk(acc[i][2], acc[i][3]);
    *(uint2*)(P + (size_t)node * 256 + c0) = make_uint2(lo, hi);
  }
}

// ============ K2: fused edge kernel — fragment-resident, intra-wave ============
__global__ __launch_bounds__(256) void k2_edge(const unsigned short* __restrict__ P,
                                               const float* __restrict__ edge_attr,
                                               const float* __restrict__ pos,
                                               const int* __restrict__ ei,
                                               const int* __restrict__ perm,
                                               const unsigned short* __restrict__ W1ef,
                                               const unsigned short* __restrict__ W2f,
                                               const float* __restrict__ b1,
                                               const float* __restrict__ ln1g,
                                               const float* __restrict__ ln1b,
                                               float* __restrict__ sums) {
  __shared__ unsigned short htile[64][136];   // h (bf16), then msg (bf16) in place
  __shared__ float4 relv[64];
  __shared__ int dsts[64], srcs[64], eids[64];
  __shared__ float b1s[128], g1s[128], bb1s[128];

  const int t = threadIdx.x, lane = t & 63, w = t >> 6;
  const int kg = lane >> 4, li = lane & 15;
  const int e0 = blockIdx.x * 64;   // 12500*64 = 800000 exact
  const int el = w * 16 + li;       // this lane's edge row (owned by wave w)

  if (t < 128) { b1s[t] = b1[t]; g1s[t] = ln1g[t]; bb1s[t] = ln1b[t]; }
  if (t < 64) {
    const int e = perm[e0 + t];
    eids[t] = e;
    const int s = ei[e], d = ei[EE + e];
    srcs[t] = s; dsts[t] = d;
    const float rx = (pos[3 * s + 0] - pos[3 * d + 0]) * 0.2f;
    const float ry = (pos[3 * s + 1] - pos[3 * d + 1]) * 0.2f;
    const float rz = (pos[3 * s + 2] - pos[3 * d + 2]) * 0.2f;
    relv[t] = make_float4(rx, ry, rz, rx * rx + ry * ry + rz * rz);
  }
  __syncthreads();   // the ONLY block barrier

  // ---- fragment-layout P gathers (dst + src), issued early ----
  const int dn = dsts[el], sn = srcs[el];
  const unsigned short* pdp = P + (size_t)dn * 256 + kg * 4;
  const unsigned short* psp = P + (size_t)sn * 256 + 128 + kg * 4;
  uint2 pdv[8], psv[8];
#pragma unroll
  for (int cf = 0; cf < 8; ++cf) {
    pdv[cf] = *(const uint2*)(pdp + cf * 16);
    psv[cf] = *(const uint2*)(psp + cf * 16);
  }

  // ---- A1: edge-part = (ea|geom) @ W1[256:276] via MFMA (transposed D) ----
  bf16x8 bfrag;
  if (kg < 2) {
    const float* ep = edge_attr + (size_t)eids[el] * 16 + kg * 8;
    const float4 u = *(const float4*)ep, v = *(const float4*)(ep + 4);
    bfrag = pack8(u.x, u.y, u.z, u.w, v.x, v.y, v.z, v.w);
  } else if (kg == 2) {
    const float4 rv = relv[el];
    bfrag = pack8(rv.x, rv.y, rv.z, rv.w, 0.f, 0.f, 0.f, 0.f);
  } else {
    bfrag = pack8(0.f, 0.f, 0.f, 0.f, 0.f, 0.f, 0.f, 0.f);
  }
  const f32x4 zf = {0.0f, 0.0f, 0.0f, 0.0f};
  f32x4 acc[8];
#pragma unroll
  for (int cf = 0; cf < 8; ++cf) {
    const bf16x8 af = *(const bf16x8*)(W1ef + (size_t)cf * 512 + lane * 8);
    acc[cf] = __builtin_amdgcn_mfma_f32_16x16x32_bf16(af, bfrag, zf, 0, 0, 0);
  }

  // ---- A2: pre = acc + Pd + Ps + b1 -> LN (shfl) -> SiLU -> htile ----
  float pre[8][4];
  float s1 = 0.0f, s2 = 0.0f;
#pragma unroll
  for (int cf = 0; cf < 8; ++cf) {
    const float4 bb = *(const float4*)&b1s[cf * 16 + kg * 4];
    const float p0 = uasf(pdv[cf].x << 16) + uasf(psv[cf].x << 16);
    const float p1 = uasf(pdv[cf].x & 0xffff0000u) + uasf(psv[cf].x & 0xffff0000u);
    const float p2 = uasf(pdv[cf].y << 16) + uasf(psv[cf].y << 16);
    const float p3 = uasf(pdv[cf].y & 0xffff0000u) + uasf(psv[cf].y & 0xffff0000u);
    const float v0 = acc[cf][0] + p0 + bb.x;
    const float v1 = acc[cf][1] + p1 + bb.y;
    const float v2 = acc[cf][2] + p2 + bb.z;
    const float v3 = acc[cf][3] + p3 + bb.w;
    pre[cf][0] = v0; pre[cf][1] = v1; pre[cf][2] = v2; pre[cf][3] = v3;
    s1 += (v0 + v1) + (v2 + v3);
    s2 += (v0 * v0 + v1 * v1) + (v2 * v2 + v3 * v3);
  }
  s1 += __shfl_xor(s1, 16); s2 += __shfl_xor(s2, 16);
  s1 += __shfl_xor(s1, 32); s2 += __shfl_xor(s2, 32);
  const float m = s1 * (1.0f / 128.0f);
  const float var = s2 * (1.0f / 128.0f) - m * m;
  const float rstd = rsqrtf(var + 1e-5f);
#pragma unroll
  for (int cf = 0; cf < 8; ++cf) {
    const float4 gg = *(const float4*)&g1s[cf * 16 + kg * 4];
    const float4 be = *(const float4*)&bb1s[cf * 16 + kg * 4];
    float y0 = gg.x * ((pre[cf][0] - m) * rstd) + be.x;
    float y1 = gg.y * ((pre[cf][1] - m) * rstd) + be.y;
    float y2 = gg.z * ((pre[cf][2] - m) * rstd) + be.z;
    float y3 = gg.w * ((pre[cf][3] - m) * rstd) + be.w;
    y0 *= sigm(y0); y1 *= sigm(y1); y2 *= sigm(y2); y3 *= sigm(y3);
    *(uint2*)&htile[el][cf * 16 + kg * 4] = make_uint2(cvtpk(y0, y1), cvtpk(y2, y3));
  }

  // intra-wave LDS ordering: wave's own writes must land before cross-lane reads
  asm volatile("s_waitcnt lgkmcnt(0)" ::: "memory");
  __builtin_amdgcn_sched_barrier(0);

  // ---- B: msg^T = W2^T x h (own row only), write msg back in place ----
  bf16x8 hfr[4];
#pragma unroll
  for (int ks = 0; ks < 4; ++ks)
    hfr[ks] = *(const bf16x8*)&htile[el][ks * 32 + kg * 8];

  f32x4 macc[8];
#pragma unroll
  for (int cf = 0; cf < 8; ++cf) macc[cf] = zf;
#pragma unroll
  for (int ks = 0; ks < 4; ++ks) {
#pragma unroll
    for (int cf = 0; cf < 8; ++cf) {
      const bf16x8 wf = *(const bf16x8*)(W2f + (size_t)((cf << 2) | ks) * 512 + lane * 8);
      macc[cf] = __builtin_amdgcn_mfma_f32_16x16x32_bf16(wf, hfr[ks], macc[cf], 0, 0, 0);
    }
  }
#pragma unroll
  for (int cf = 0; cf < 8; ++cf) {
    *(uint2*)&htile[el][cf * 16 + kg * 4] =
        make_uint2(cvtpk(macc[cf][0], macc[cf][1]), cvtpk(macc[cf][2], macc[cf][3]));
  }

  asm volatile("s_waitcnt lgkmcnt(0)" ::: "memory");
  __builtin_amdgcn_sched_barrier(0);

  // ---- C: segmented run-reduce over own wave's 16 sorted rows, 2 cols/lane ----
  {
    const int q0e = w * 16;
    const int c2 = lane * 2;
    int rd = __builtin_amdgcn_readfirstlane(dsts[q0e]);
    unsigned v = *(const unsigned*)&htile[q0e][c2];
    float r0 = uasf(v << 16), r1 = uasf(v & 0xffff0000u);
#pragma unroll
    for (int i = 1; i < 16; ++i) {
      const int d = __builtin_amdgcn_readfirstlane(dsts[q0e + i]);
      const unsigned vv = *(const unsigned*)&htile[q0e + i][c2];
      const float f0 = uasf(vv << 16), f1 = uasf(vv & 0xffff0000u);
      if (d == rd) {
        r0 += f0; r1 += f1;
      } else {
        atomicAdd(sums + (size_t)rd * 128 + c2, r0);
        atomicAdd(sums + (size_t)rd * 128 + c2 + 1, r1);
        rd = d; r0 = f0; r1 = f1;
      }
    }
    atomicAdd(sums + (size_t)rd * 128 + c2, r0);
    atomicAdd(sums + (size_t)rd * 128 + c2 + 1, r1);
  }
}

// ============ K3: GRU + LN2 (MFMA), 16 nodes per block ============
__global__ __launch_bounds__(256) void k3_gru(const float* __restrict__ x,
                                              const float* __restrict__ sums,
                                              const int* __restrict__ deg,
                                              const unsigned short* __restrict__ Wihf,
                                              const unsigned short* __restrict__ Whhf,
                                              const float* __restrict__ bih,
                                              const float* __restrict__ bhh,
                                              const float* __restrict__ b2,
                                              const float* __restrict__ ln2g,
                                              const float* __restrict__ ln2b,
                                              float* __restrict__ out) {
  __shared__ unsigned short aggb[16][136];   // agg bf16
  __shared__ unsigned short Ss[16][776];     // [gi(384) | gh(384)] bf16
  const int t = threadIdx.x, lane = t & 63, w = t >> 6;
  const int kg = lane >> 4, li = lane & 15;
  const int n0 = blockIdx.x * 16;   // 3125*16 = 50000 exact

  // stage agg = sums/max(deg,1) + (deg>0)*b2
  {
    const int nl = t >> 4, c0 = (t & 15) * 8;
    const int gn = n0 + nl;
    const int dc = deg[gn];
    const float inv = 1.0f / fmaxf((float)dc, 1.0f);
    const float bsc = (dc > 0) ? 1.0f : 0.0f;
    const float* sp = sums + (size_t)gn * 128 + c0;
    const float4 u = *(const float4*)sp, v = *(const float4*)(sp + 4);
    const float4 bu = *(const float4*)(b2 + c0), bv = *(const float4*)(b2 + c0 + 4);
    const unsigned o0 = cvtpk(u.x * inv + bsc * bu.x, u.y * inv + bsc * bu.y);
    const unsigned o1 = cvtpk(u.z * inv + bsc * bu.z, u.w * inv + bsc * bu.w);
    const unsigned o2 = cvtpk(v.x * inv + bsc * bv.x, v.y * inv + bsc * bv.y);
    const unsigned o3 = cvtpk(v.z * inv + bsc * bv.z, v.w * inv + bsc * bv.w);
    *(uint4*)&aggb[nl][c0] = make_uint4(o0, o1, o2, o3);
  }
  __syncthreads();

  // waves 0-1: gi = agg@Wih^T ; waves 2-3: gh = x@Whh^T
  const int isH = w >> 1;
  const int ctbase = (w & 1) * 12;
  const unsigned short* Wf = isH ? Whhf : Wihf;
  const float* bias = isH ? bhh : bih;
  const f32x4 zf = {0.0f, 0.0f, 0.0f, 0.0f};
  f32x4 acc[12];
#pragma unroll
  for (int i = 0; i < 12; ++i) acc[i] = zf;
#pragma unroll
  for (int ks = 0; ks < 4; ++ks) {
    bf16x8 bfrag;
    if (isH) {
      const float* xp = x + (size_t)(n0 + li) * 128 + ks * 32 + kg * 8;
      const float4 u = *(const float4*)xp, v = *(const float4*)(xp + 4);
      bfrag = pack8(u.x, u.y, u.z, u.w, v.x, v.y, v.z, v.w);
    } else {
      bfrag = *(const bf16x8*)&aggb[li][ks * 32 + kg * 8];
    }
#pragma unroll
    for (int i = 0; i < 12; ++i) {
      const int ct = ctbase + i;
      const bf16x8 af = *(const bf16x8*)(Wf + (size_t)(ct * 4 + ks) * 512 + lane * 8);
      acc[i] = __builtin_amdgcn_mfma_f32_16x16x32_bf16(af, bfrag, acc[i], 0, 0, 0);
    }
  }
#pragma unroll
  for (int i = 0; i < 12; ++i) {
    const int ocol = (ctbase + i) * 16 + kg * 4;
    const float4 bb = *(const float4*)(bias + ocol);
    const int col = isH * 384 + ocol;
    const unsigned lo = cvtpk(acc[i][0] + bb.x, acc[i][1] + bb.y);
    const unsigned hi = cvtpk(acc[i][2] + bb.z, acc[i][3] + bb.w);
    *(uint2*)&Ss[li][col] = make_uint2(lo, hi);
  }
  __syncthreads();

  // gates + residual + LN2
  const int nl = t >> 4, q0 = (t & 15) * 8;
  const int gn = n0 + nl;
  float xv[8];
  *(float4*)&xv[0] = *(const float4*)(x + (size_t)gn * 128 + q0);
  *(float4*)&xv[4] = *(const float4*)(x + (size_t)gn * 128 + q0 + 4);
  const uint4 gir = *(const uint4*)&Ss[nl][q0];
  const uint4 giz = *(const uint4*)&Ss[nl][q0 + 128];
  const uint4 gin = *(const uint4*)&Ss[nl][q0 + 256];
  const uint4 ghr = *(const uint4*)&Ss[nl][q0 + 384];
  const uint4 ghz = *(const uint4*)&Ss[nl][q0 + 512];
  const uint4 ghn = *(const uint4*)&Ss[nl][q0 + 640];
  const unsigned GIR[4] = {gir.x, gir.y, gir.z, gir.w};
  const unsigned GIZ[4] = {giz.x, giz.y, giz.z, giz.w};
  const unsigned GIN[4] = {gin.x, gin.y, gin.z, gin.w};
  const unsigned GHR[4] = {ghr.x, ghr.y, ghr.z, ghr.w};
  const unsigned GHZ[4] = {ghz.x, ghz.y, ghz.z, ghz.w};
  const unsigned GHN[4] = {ghn.x, ghn.y, ghn.z, ghn.w};
  float vb[8];
  float s1 = 0.0f, s2 = 0.0f;
#pragma unroll
  for (int j2 = 0; j2 < 4; ++j2) {
#pragma unroll
    for (int hl = 0; hl < 2; ++hl) {
      const int jj = j2 * 2 + hl;
      const unsigned sh = hl * 16;
      const float girv = bf2f((GIR[j2] >> sh) & 0xffffu);
      const float gizv = bf2f((GIZ[j2] >> sh) & 0xffffu);
      const float ginv = bf2f((GIN[j2] >> sh) & 0xffffu);
      const float ghrv = bf2f((GHR[j2] >> sh) & 0xffffu);
      const float ghzv = bf2f((GHZ[j2] >> sh) & 0xffffu);
      const float ghnv = bf2f((GHN[j2] >> sh) & 0xffffu);
      const float r = sigm(girv + ghrv);
      const float z = sigm(gizv + ghzv);
      const float nv = tanhf(ginv + r * ghnv);
      const float v = xv[jj] + (1.0f - z) * nv + z * xv[jj];
      vb[jj] = v; s1 += v; s2 += v * v;
    }
  }
  s1 += __shfl_xor(s1, 1); s2 += __shfl_xor(s2, 1);
  s1 += __shfl_xor(s1, 2); s2 += __shfl_xor(s2, 2);
  s1 += __shfl_xor(s1, 4); s2 += __shfl_xor(s2, 4);
  s1 += __shfl_xor(s1, 8); s2 += __shfl_xor(s2, 8);
  const float m = s1 * (1.0f / 128.0f);
  const float var = s2 * (1.0f / 128.0f) - m * m;
  const float rstd = rsqrtf(var + 1e-5f);
  float ov[8];
#pragma unroll
  for (int j = 0; j < 8; ++j)
    ov[j] = ln2g[q0 + j] * ((vb[j] - m) * rstd) + ln2b[q0 + j];
  *(float4*)(out + (size_t)gn * 128 + q0) = make_float4(ov[0], ov[1], ov[2], ov[3]);
  *(float4*)(out + (size_t)gn * 128 + q0 + 4) = make_float4(ov[4], ov[5], ov[6], ov[7]);
}

extern "C" void kernel_launch(void* const* d_in, const int* in_sizes, int n_in,
                              void* d_out, int out_size, void* d_ws, size_t ws_size,
                              hipStream_t stream) {
  const float* x         = (const float*)d_in[0];
  const float* edge_attr = (const float*)d_in[1];
  const float* pos       = (const float*)d_in[2];
  const float* W1        = (const float*)d_in[3];
  const float* b1        = (const float*)d_in[4];
  const float* ln1g      = (const float*)d_in[5];
  const float* ln1b      = (const float*)d_in[6];
  const float* W2        = (const float*)d_in[7];
  const float* b2        = (const float*)d_in[8];
  const float* Wih       = (const float*)d_in[9];
  const float* bih       = (const float*)d_in[10];
  const float* Whh       = (const float*)d_in[11];
  const float* bhh       = (const float*)d_in[12];
  const float* ln2g      = (const float*)d_in[13];
  const float* ln2b      = (const float*)d_in[14];
  const int*   ei        = (const int*)d_in[15];
  float* out = (float*)d_out;

  // ws layout (bytes)
  float*          sums  = (float*)d_ws;                                   // 25,600,000
  unsigned short* Pb    = (unsigned short*)((char*)d_ws + 25600000);      // 25,600,000
  unsigned short* frags = (unsigned short*)((char*)d_ws + 51200000);      //    303,104
  int*            deg   = (int*)((char*)d_ws + 51600000);                 //    200,000
  int*            cur   = (int*)((char*)d_ws + 51800000);                 //    200,000
  int*            offs  = (int*)((char*)d_ws + 52000000);                 //    200,000
  int*            bsum  = (int*)((char*)d_ws + 52200000);                 //        784
  int*            boff  = (int*)((char*)d_ws + 52204096);                 //        784
  int*            perm  = (int*)((char*)d_ws + 52300000);                 //  3,200,000
  unsigned short* W1ef = frags;               // 8 frags
  unsigned short* W2f  = frags + 8 * 512;     // 32 frags
  unsigned short* W1nf = frags + 40 * 512;    // 64 frags
  unsigned short* Wihf = frags + 104 * 512;   // 96 frags
  unsigned short* Whhf = frags + 200 * 512;   // 96 frags

  hipMemsetAsync(sums, 0, (size_t)NN * 128 * sizeof(float), stream);
  hipMemsetAsync(deg, 0, 2 * 200000, stream);   // deg + cur

  k0_prep<<<296, 64, 0, stream>>>(W1, W2, Wih, Whh, frags);
  k_hist<<<3125, 256, 0, stream>>>(ei, deg);
  kA_partial<<<196, 256, 0, stream>>>(deg, bsum);
  kB_scan<<<1, 256, 0, stream>>>(bsum, boff);
  kC_offs<<<196, 256, 0, stream>>>(deg, boff, offs);
  k_scatter<<<3125, 256, 0, stream>>>(ei, offs, cur, perm);
  k1_node_pre<<<3125, 256, 0, stream>>>(x, W1nf, Pb);
  k2_edge<<<12500, 256, 0, stream>>>(Pb, edge_attr, pos, ei, perm, W1ef, W2f,
                                     b1, ln1g, ln1b, sums);
  k3_gru<<<3125, 256, 0, stream>>>(x, sums, deg, Wihf, Whhf, bih, bhh, b2,
                                   ln2g, ln2b, out);
}

// Round 6
// 345.318 us; speedup vs baseline: 1.0745x; 1.0745x over previous
//
#include <hip/hip_runtime.h>
#include <math.h>

#define NN 50000
#define EE 800000

typedef __attribute__((ext_vector_type(8))) short bf16x8;
typedef __attribute__((ext_vector_type(4))) float f32x4;

__device__ __forceinline__ float bf2f(unsigned int h16) {
  union { unsigned u; float f; } z; z.u = h16 << 16; return z.f;
}
__device__ __forceinline__ float uasf(unsigned u) {
  union { unsigned u; float f; } z; z.u = u; return z.f;
}
__device__ __forceinline__ unsigned cvtpk(float lo, float hi) {
  unsigned r;
  asm("v_cvt_pk_bf16_f32 %0, %1, %2" : "=v"(r) : "v"(lo), "v"(hi));
  return r;
}
__device__ __forceinline__ float sigm(float v) { return 1.0f / (1.0f + __expf(-v)); }

__device__ __forceinline__ bf16x8 pack8(float a0, float a1, float a2, float a3,
                                        float a4, float a5, float a6, float a7) {
  union { unsigned u[4]; bf16x8 v; } z;
  z.u[0] = cvtpk(a0, a1); z.u[1] = cvtpk(a2, a3);
  z.u[2] = cvtpk(a4, a5); z.u[3] = cvtpk(a6, a7);
  return z.v;
}

// ============ K0: pack all weights into bf16 MFMA A-fragments ============
__global__ __launch_bounds__(64) void k0_prep(const float* __restrict__ W1,
                                              const float* __restrict__ W2,
                                              const float* __restrict__ Wih,
                                              const float* __restrict__ Whh,
                                              unsigned short* __restrict__ frags) {
  const int f = blockIdx.x, l = threadIdx.x;
  const int c16 = l & 15, kg = l >> 4;
  float v[8];
  if (f < 8) {
    const int c = f * 16 + c16;
#pragma unroll
    for (int j = 0; j < 8; ++j) {
      const int k = kg * 8 + j;
      v[j] = (k < 20) ? W1[(256 + k) * 128 + c] : 0.0f;
    }
  } else if (f < 40) {
    const int lf = f - 8, ct = lf >> 2, ks = lf & 3, c = ct * 16 + c16;
#pragma unroll
    for (int j = 0; j < 8; ++j) { const int k = ks * 32 + kg * 8 + j; v[j] = W2[k * 128 + c]; }
  } else if (f < 104) {
    const int lf = f - 40, ct = lf >> 2, ks = lf & 3, c = ct * 16 + c16;
#pragma unroll
    for (int j = 0; j < 8; ++j) {
      const int k = ks * 32 + kg * 8 + j;
      v[j] = (c < 128) ? W1[k * 128 + c] : W1[(128 + k) * 128 + (c - 128)];
    }
  } else if (f < 200) {
    const int lf = f - 104, ct = lf >> 2, ks = lf & 3, c = ct * 16 + c16;
#pragma unroll
    for (int j = 0; j < 8; ++j) { const int k = ks * 32 + kg * 8 + j; v[j] = Wih[c * 128 + k]; }
  } else {
    const int lf = f - 200, ct = lf >> 2, ks = lf & 3, c = ct * 16 + c16;
#pragma unroll
    for (int j = 0; j < 8; ++j) { const int k = ks * 32 + kg * 8 + j; v[j] = Whh[c * 128 + k]; }
  }
  *(bf16x8*)(frags + (size_t)f * 512 + l * 8) =
      pack8(v[0], v[1], v[2], v[3], v[4], v[5], v[6], v[7]);
}

// ============ counting sort of edges by dst ============
__global__ __launch_bounds__(256) void k_hist(const int* __restrict__ ei,
                                              int* __restrict__ deg) {
  const int e = blockIdx.x * 256 + threadIdx.x;
  if (e < EE) atomicAdd(&deg[ei[EE + e]], 1);
}

__global__ __launch_bounds__(256) void kA_partial(const int* __restrict__ deg,
                                                  int* __restrict__ bsum) {
  const int i = blockIdx.x * 256 + threadIdx.x;
  int v = (i < NN) ? deg[i] : 0;
#pragma unroll
  for (int o = 32; o > 0; o >>= 1) v += __shfl_down(v, o);
  __shared__ int wsum[4];
  if ((threadIdx.x & 63) == 0) wsum[threadIdx.x >> 6] = v;
  __syncthreads();
  if (threadIdx.x == 0) bsum[blockIdx.x] = wsum[0] + wsum[1] + wsum[2] + wsum[3];
}

__global__ __launch_bounds__(256) void kB_scan(const int* __restrict__ bsum,
                                               int* __restrict__ boff) {
  __shared__ int s[256];
  const int t = threadIdx.x;
  const int orig = (t < 196) ? bsum[t] : 0;
  s[t] = orig;
  __syncthreads();
  for (int o = 1; o < 256; o <<= 1) {
    const int v = (t >= o) ? s[t - o] : 0;
    __syncthreads();
    s[t] += v;
    __syncthreads();
  }
  if (t < 196) boff[t] = s[t] - orig;
}

__global__ __launch_bounds__(256) void kC_offs(const int* __restrict__ deg,
                                               const int* __restrict__ boff,
                                               int* __restrict__ offs) {
  __shared__ int s[256];
  const int t = threadIdx.x, i = blockIdx.x * 256 + t;
  const int orig = (i < NN) ? deg[i] : 0;
  s[t] = orig;
  __syncthreads();
  for (int o = 1; o < 256; o <<= 1) {
    const int v = (t >= o) ? s[t - o] : 0;
    __syncthreads();
    s[t] += v;
    __syncthreads();
  }
  if (i < NN) offs[i] = boff[blockIdx.x] + s[t] - orig;
}

__global__ __launch_bounds__(256) void k_scatter(const int* __restrict__ ei,
                                                 const int* __restrict__ offs,
                                                 int* __restrict__ cur,
                                                 int* __restrict__ perm) {
  const int e = blockIdx.x * 256 + threadIdx.x;
  if (e < EE) {
    const int d = ei[EE + e];
    const int p = atomicAdd(&cur[d], 1);
    perm[offs[d] + p] = e;
  }
}

// ============ K1: P[n][0:256] = x @ [W1_dst | W1_src]  (bf16 out) ============
__global__ __launch_bounds__(256) void k1_node_pre(const float* __restrict__ x,
                                                   const unsigned short* __restrict__ W1nf,
                                                   unsigned short* __restrict__ P) {
  const int t = threadIdx.x, lane = t & 63, w = t >> 6;
  const int kg = lane >> 4, li = lane & 15;
  const int node = blockIdx.x * 16 + li;   // 3125*16 = 50000 exact
  const f32x4 zf = {0.0f, 0.0f, 0.0f, 0.0f};
  f32x4 acc[4] = {zf, zf, zf, zf};
#pragma unroll
  for (int ks = 0; ks < 4; ++ks) {
    const float* xp = x + (size_t)node * 128 + ks * 32 + kg * 8;
    const float4 u = *(const float4*)xp, v = *(const float4*)(xp + 4);
    const bf16x8 xb = pack8(u.x, u.y, u.z, u.w, v.x, v.y, v.z, v.w);
#pragma unroll
    for (int i = 0; i < 4; ++i) {
      const int ct = w * 4 + i;
      const bf16x8 af = *(const bf16x8*)(W1nf + (size_t)(ct * 4 + ks) * 512 + lane * 8);
      acc[i] = __builtin_amdgcn_mfma_f32_16x16x32_bf16(af, xb, acc[i], 0, 0, 0);
    }
  }
#pragma unroll
  for (int i = 0; i < 4; ++i) {
    const int c0 = (w * 4 + i) * 16 + kg * 4;
    const unsigned lo = cvtpk(acc[i][0], acc[i][1]);
    const unsigned hi = cvtpk(acc[i][2], acc[i][3]);
    *(uint2*)(P + (size_t)node * 256 + c0) = make_uint2(lo, hi);
  }
}

// ============ K2: fused edge kernel (round-4 structure + cvtpk/1-op unpack) ============
__global__ __launch_bounds__(256) void k2_edge(const unsigned short* __restrict__ P,
                                               const float* __restrict__ edge_attr,
                                               const float* __restrict__ pos,
                                               const int* __restrict__ ei,
                                               const int* __restrict__ perm,
                                               const unsigned short* __restrict__ W1ef,
                                               const unsigned short* __restrict__ W2f,
                                               const float* __restrict__ b1,
                                               const float* __restrict__ ln1g,
                                               const float* __restrict__ ln1b,
                                               float* __restrict__ sums) {
  __shared__ unsigned short htile[64][136];   // h (bf16), later reused for msg (bf16)
  __shared__ float4 relv[64];
  __shared__ int dsts[64], srcs[64], eids[64];
  __shared__ float b1s[128], g1s[128], bb1s[128];

  const int t = threadIdx.x, lane = t & 63, w = t >> 6;
  const int kg = lane >> 4, li = lane & 15;
  const int e0 = blockIdx.x * 64;   // 12500*64 = 800000 exact

  if (t < 128) { b1s[t] = b1[t]; g1s[t] = ln1g[t]; bb1s[t] = ln1b[t]; }
  if (t < 64) {
    const int e = perm[e0 + t];
    eids[t] = e;
    const int s = ei[e], d = ei[EE + e];
    srcs[t] = s; dsts[t] = d;
    const float rx = (pos[3 * s + 0] - pos[3 * d + 0]) * 0.2f;
    const float ry = (pos[3 * s + 1] - pos[3 * d + 1]) * 0.2f;
    const float rz = (pos[3 * s + 2] - pos[3 * d + 2]) * 0.2f;
    relv[t] = make_float4(rx, ry, rz, rx * rx + ry * ry + rz * rz);
  }
  __syncthreads();

  // issue P gathers early (A2 mapping: 4 threads per edge, 32 cols each)
  const int e2 = t >> 2, cg = t & 3;
  const int dn = dsts[e2], sn = srcs[e2];
  const uint4* pdp = (const uint4*)(P + (size_t)dn * 256 + cg * 32);
  const uint4* psp = (const uint4*)(P + (size_t)sn * 256 + 128 + cg * 32);
  uint4 PV[4] = {pdp[0], pdp[1], pdp[2], pdp[3]};
  uint4 SV[4] = {psp[0], psp[1], psp[2], psp[3]};

  // ---- A1: pre_edgepart = (ea|geom) @ W1[256:276]  via MFMA (transposed D) ----
  const int el = w * 16 + li;
  bf16x8 bfrag;
  if (kg < 2) {
    const float* ep = edge_attr + (size_t)eids[el] * 16 + kg * 8;
    const float4 u = *(const float4*)ep, v = *(const float4*)(ep + 4);
    bfrag = pack8(u.x, u.y, u.z, u.w, v.x, v.y, v.z, v.w);
  } else if (kg == 2) {
    const float4 rv = relv[el];
    bfrag = pack8(rv.x, rv.y, rv.z, rv.w, 0.f, 0.f, 0.f, 0.f);
  } else {
    bfrag = pack8(0.f, 0.f, 0.f, 0.f, 0.f, 0.f, 0.f, 0.f);
  }
  const f32x4 zf = {0.0f, 0.0f, 0.0f, 0.0f};
#pragma unroll
  for (int cf = 0; cf < 8; ++cf) {
    const bf16x8 af = *(const bf16x8*)(W1ef + (size_t)cf * 512 + lane * 8);
    const f32x4 d = __builtin_amdgcn_mfma_f32_16x16x32_bf16(af, bfrag, zf, 0, 0, 0);
    const int c0 = cf * 16 + kg * 4;
    *(uint2*)&htile[el][c0] = make_uint2(cvtpk(d[0], d[1]), cvtpk(d[2], d[3]));
  }
  __syncthreads();

  // ---- A2: pre = htile + Pd + Ps + b1 -> LN -> SiLU -> htile (in place) ----
  {
    float pre[32];
    const uint4* hp = (const uint4*)&htile[e2][cg * 32];
    uint4 HV[4] = {hp[0], hp[1], hp[2], hp[3]};
    float s1 = 0.0f, s2 = 0.0f;
#pragma unroll
    for (int q = 0; q < 4; ++q) {
      const unsigned hx[4] = {HV[q].x, HV[q].y, HV[q].z, HV[q].w};
      const unsigned px[4] = {PV[q].x, PV[q].y, PV[q].z, PV[q].w};
      const unsigned sx[4] = {SV[q].x, SV[q].y, SV[q].z, SV[q].w};
#pragma unroll
      for (int j2 = 0; j2 < 4; ++j2) {
        const int idx = q * 8 + j2 * 2;
        const float v0 = uasf(hx[j2] << 16) + uasf(px[j2] << 16) +
                         uasf(sx[j2] << 16) + b1s[cg * 32 + idx];
        const float v1 = uasf(hx[j2] & 0xffff0000u) + uasf(px[j2] & 0xffff0000u) +
                         uasf(sx[j2] & 0xffff0000u) + b1s[cg * 32 + idx + 1];
        pre[idx] = v0; pre[idx + 1] = v1;
        s1 += v0 + v1; s2 += v0 * v0 + v1 * v1;
      }
    }
    s1 += __shfl_xor(s1, 1); s2 += __shfl_xor(s2, 1);
    s1 += __shfl_xor(s1, 2); s2 += __shfl_xor(s2, 2);
    const float m = s1 * (1.0f / 128.0f);
    const float var = s2 * (1.0f / 128.0f) - m * m;
    const float rstd = rsqrtf(var + 1e-5f);
#pragma unroll
    for (int q = 0; q < 4; ++q) {
      unsigned ow[4];
#pragma unroll
      for (int j2 = 0; j2 < 4; ++j2) {
        const int idx = q * 8 + j2 * 2;
        float y0 = g1s[cg * 32 + idx] * ((pre[idx] - m) * rstd) + bb1s[cg * 32 + idx];
        float y1 = g1s[cg * 32 + idx + 1] * ((pre[idx + 1] - m) * rstd) + bb1s[cg * 32 + idx + 1];
        y0 *= sigm(y0); y1 *= sigm(y1);
        ow[j2] = cvtpk(y0, y1);
      }
      *(uint4*)&htile[e2][cg * 32 + q * 8] = make_uint4(ow[0], ow[1], ow[2], ow[3]);
    }
  }
  __syncthreads();

  // ---- B: stage h-frags in regs, MFMA msg^T, write msg (bf16) back to htile ----
  {
    bf16x8 hfr[4];
#pragma unroll
    for (int ks = 0; ks < 4; ++ks)
      hfr[ks] = *(const bf16x8*)&htile[w * 16 + li][ks * 32 + kg * 8];

    f32x4 acc[8];
#pragma unroll
    for (int cf = 0; cf < 8; ++cf) acc[cf] = zf;
#pragma unroll
    for (int ks = 0; ks < 4; ++ks) {
#pragma unroll
      for (int cf = 0; cf < 8; ++cf) {
        const bf16x8 wf = *(const bf16x8*)(W2f + (size_t)((cf << 2) | ks) * 512 + lane * 8);
        acc[cf] = __builtin_amdgcn_mfma_f32_16x16x32_bf16(wf, hfr[ks], acc[cf], 0, 0, 0);
      }
    }
#pragma unroll
    for (int cf = 0; cf < 8; ++cf) {
      const int c0 = cf * 16 + kg * 4;
      *(uint2*)&htile[w * 16 + li][c0] =
          make_uint2(cvtpk(acc[cf][0], acc[cf][1]), cvtpk(acc[cf][2], acc[cf][3]));
    }
  }
  __syncthreads();

  // ---- C: segmented-run reduction over sorted dsts, coalesced flush ----
  {
    const int c = t & 127;            // column
    const int h0 = (t >> 7) * 32;     // edges h0..h0+31 (wave-uniform)
    int rd = dsts[h0];
    float racc = bf2f((unsigned)htile[h0][c]);
#pragma unroll
    for (int i = 1; i < 32; ++i) {
      const int ee = h0 + i;
      const int d = dsts[ee];
      const float v = bf2f((unsigned)htile[ee][c]);
      if (d == rd) {
        racc += v;
      } else {
        atomicAdd(sums + (size_t)rd * 128 + c, racc);
        rd = d; racc = v;
      }
    }
    atomicAdd(sums + (size_t)rd * 128 + c, racc);
  }
}

// ============ K3: GRU + LN2 (MFMA), 16 nodes per block ============
__global__ __launch_bounds__(256) void k3_gru(const float* __restrict__ x,
                                              const float* __restrict__ sums,
                                              const int* __restrict__ deg,
                                              const unsigned short* __restrict__ Wihf,
                                              const unsigned short* __restrict__ Whhf,
                                              const float* __restrict__ bih,
                                              const float* __restrict__ bhh,
                                              const float* __restrict__ b2,
                                              const float* __restrict__ ln2g,
                                              const float* __restrict__ ln2b,
                                              float* __restrict__ out) {
  __shared__ unsigned short aggb[16][136];   // agg bf16
  __shared__ unsigned short Ss[16][776];     // [gi(384) | gh(384)] bf16
  const int t = threadIdx.x, lane = t & 63, w = t >> 6;
  const int kg = lane >> 4, li = lane & 15;
  const int n0 = blockIdx.x * 16;   // 3125*16 = 50000 exact

  // stage agg = sums/max(deg,1) + (deg>0)*b2
  {
    const int nl = t >> 4, c0 = (t & 15) * 8;
    const int gn = n0 + nl;
    const int dc = deg[gn];
    const float inv = 1.0f / fmaxf((float)dc, 1.0f);
    const float bsc = (dc > 0) ? 1.0f : 0.0f;
    const float* sp = sums + (size_t)gn * 128 + c0;
    const float4 u = *(const float4*)sp, v = *(const float4*)(sp + 4);
    const float4 bu = *(const float4*)(b2 + c0), bv = *(const float4*)(b2 + c0 + 4);
    const unsigned o0 = cvtpk(u.x * inv + bsc * bu.x, u.y * inv + bsc * bu.y);
    const unsigned o1 = cvtpk(u.z * inv + bsc * bu.z, u.w * inv + bsc * bu.w);
    const unsigned o2 = cvtpk(v.x * inv + bsc * bv.x, v.y * inv + bsc * bv.y);
    const unsigned o3 = cvtpk(v.z * inv + bsc * bv.z, v.w * inv + bsc * bv.w);
    *(uint4*)&aggb[nl][c0] = make_uint4(o0, o1, o2, o3);
  }
  __syncthreads();

  // waves 0-1: gi = agg@Wih^T ; waves 2-3: gh = x@Whh^T
  const int isH = w >> 1;
  const int ctbase = (w & 1) * 12;
  const unsigned short* Wf = isH ? Whhf : Wihf;
  const float* bias = isH ? bhh : bih;
  const f32x4 zf = {0.0f, 0.0f, 0.0f, 0.0f};
  f32x4 acc[12];
#pragma unroll
  for (int i = 0; i < 12; ++i) acc[i] = zf;
#pragma unroll
  for (int ks = 0; ks < 4; ++ks) {
    bf16x8 bfrag;
    if (isH) {
      const float* xp = x + (size_t)(n0 + li) * 128 + ks * 32 + kg * 8;
      const float4 u = *(const float4*)xp, v = *(const float4*)(xp + 4);
      bfrag = pack8(u.x, u.y, u.z, u.w, v.x, v.y, v.z, v.w);
    } else {
      bfrag = *(const bf16x8*)&aggb[li][ks * 32 + kg * 8];
    }
#pragma unroll
    for (int i = 0; i < 12; ++i) {
      const int ct = ctbase + i;
      const bf16x8 af = *(const bf16x8*)(Wf + (size_t)(ct * 4 + ks) * 512 + lane * 8);
      acc[i] = __builtin_amdgcn_mfma_f32_16x16x32_bf16(af, bfrag, acc[i], 0, 0, 0);
    }
  }
#pragma unroll
  for (int i = 0; i < 12; ++i) {
    const int ocol = (ctbase + i) * 16 + kg * 4;
    const float4 bb = *(const float4*)(bias + ocol);
    const int col = isH * 384 + ocol;
    const unsigned lo = cvtpk(acc[i][0] + bb.x, acc[i][1] + bb.y);
    const unsigned hi = cvtpk(acc[i][2] + bb.z, acc[i][3] + bb.w);
    *(uint2*)&Ss[li][col] = make_uint2(lo, hi);
  }
  __syncthreads();

  // gates + residual + LN2
  const int nl = t >> 4, q0 = (t & 15) * 8;
  const int gn = n0 + nl;
  float xv[8];
  *(float4*)&xv[0] = *(const float4*)(x + (size_t)gn * 128 + q0);
  *(float4*)&xv[4] = *(const float4*)(x + (size_t)gn * 128 + q0 + 4);
  const uint4 gir = *(const uint4*)&Ss[nl][q0];
  const uint4 giz = *(const uint4*)&Ss[nl][q0 + 128];
  const uint4 gin = *(const uint4*)&Ss[nl][q0 + 256];
  const uint4 ghr = *(const uint4*)&Ss[nl][q0 + 384];
  const uint4 ghz = *(const uint4*)&Ss[nl][q0 + 512];
  const uint4 ghn = *(const uint4*)&Ss[nl][q0 + 640];
  const unsigned GIR[4] = {gir.x, gir.y, gir.z, gir.w};
  const unsigned GIZ[4] = {giz.x, giz.y, giz.z, giz.w};
  const unsigned GIN[4] = {gin.x, gin.y, gin.z, gin.w};
  const unsigned GHR[4] = {ghr.x, ghr.y, ghr.z, ghr.w};
  const unsigned GHZ[4] = {ghz.x, ghz.y, ghz.z, ghz.w};
  const unsigned GHN[4] = {ghn.x, ghn.y, ghn.z, ghn.w};
  float vb[8];
  float s1 = 0.0f, s2 = 0.0f;
#pragma unroll
  for (int j2 = 0; j2 < 4; ++j2) {
#pragma unroll
    for (int hl = 0; hl < 2; ++hl) {
      const int jj = j2 * 2 + hl;
      const unsigned sh = hl * 16;
      const float girv = bf2f((GIR[j2] >> sh) & 0xffffu);
      const float gizv = bf2f((GIZ[j2] >> sh) & 0xffffu);
      const float ginv = bf2f((GIN[j2] >> sh) & 0xffffu);
      const float ghrv = bf2f((GHR[j2] >> sh) & 0xffffu);
      const float ghzv = bf2f((GHZ[j2] >> sh) & 0xffffu);
      const float ghnv = bf2f((GHN[j2] >> sh) & 0xffffu);
      const float r = sigm(girv + ghrv);
      const float z = sigm(gizv + ghzv);
      const float nv = tanhf(ginv + r * ghnv);
      const float v = xv[jj] + (1.0f - z) * nv + z * xv[jj];
      vb[jj] = v; s1 += v; s2 += v * v;
    }
  }
  s1 += __shfl_xor(s1, 1); s2 += __shfl_xor(s2, 1);
  s1 += __shfl_xor(s1, 2); s2 += __shfl_xor(s2, 2);
  s1 += __shfl_xor(s1, 4); s2 += __shfl_xor(s2, 4);
  s1 += __shfl_xor(s1, 8); s2 += __shfl_xor(s2, 8);
  const float m = s1 * (1.0f / 128.0f);
  const float var = s2 * (1.0f / 128.0f) - m * m;
  const float rstd = rsqrtf(var + 1e-5f);
  float ov[8];
#pragma unroll
  for (int j = 0; j < 8; ++j)
    ov[j] = ln2g[q0 + j] * ((vb[j] - m) * rstd) + ln2b[q0 + j];
  *(float4*)(out + (size_t)gn * 128 + q0) = make_float4(ov[0], ov[1], ov[2], ov[3]);
  *(float4*)(out + (size_t)gn * 128 + q0 + 4) = make_float4(ov[4], ov[5], ov[6], ov[7]);
}

extern "C" void kernel_launch(void* const* d_in, const int* in_sizes, int n_in,
                              void* d_out, int out_size, void* d_ws, size_t ws_size,
                              hipStream_t stream) {
  const float* x         = (const float*)d_in[0];
  const float* edge_attr = (const float*)d_in[1];
  const float* pos       = (const float*)d_in[2];
  const float* W1        = (const float*)d_in[3];
  const float* b1        = (const float*)d_in[4];
  const float* ln1g      = (const float*)d_in[5];
  const float* ln1b      = (const float*)d_in[6];
  const float* W2        = (const float*)d_in[7];
  const float* b2        = (const float*)d_in[8];
  const float* Wih       = (const float*)d_in[9];
  const float* bih       = (const float*)d_in[10];
  const float* Whh       = (const float*)d_in[11];
  const float* bhh       = (const float*)d_in[12];
  const float* ln2g      = (const float*)d_in[13];
  const float* ln2b      = (const float*)d_in[14];
  const int*   ei        = (const int*)d_in[15];
  float* out = (float*)d_out;

  // ws layout (bytes)
  float*          sums  = (float*)d_ws;                                   // 25,600,000
  unsigned short* Pb    = (unsigned short*)((char*)d_ws + 25600000);      // 25,600,000
  unsigned short* frags = (unsigned short*)((char*)d_ws + 51200000);      //    303,104
  int*            deg   = (int*)((char*)d_ws + 51600000);                 //    200,000
  int*            cur   = (int*)((char*)d_ws + 51800000);                 //    200,000
  int*            offs  = (int*)((char*)d_ws + 52000000);                 //    200,000
  int*            bsum  = (int*)((char*)d_ws + 52200000);                 //        784
  int*            boff  = (int*)((char*)d_ws + 52204096);                 //        784
  int*            perm  = (int*)((char*)d_ws + 52300000);                 //  3,200,000
  unsigned short* W1ef = frags;               // 8 frags
  unsigned short* W2f  = frags + 8 * 512;     // 32 frags
  unsigned short* W1nf = frags + 40 * 512;    // 64 frags
  unsigned short* Wihf = frags + 104 * 512;   // 96 frags
  unsigned short* Whhf = frags + 200 * 512;   // 96 frags

  hipMemsetAsync(sums, 0, (size_t)NN * 128 * sizeof(float), stream);
  hipMemsetAsync(deg, 0, 2 * 200000, stream);   // deg + cur

  k0_prep<<<296, 64, 0, stream>>>(W1, W2, Wih, Whh, frags);
  k_hist<<<3125, 256, 0, stream>>>(ei, deg);
  kA_partial<<<196, 256, 0, stream>>>(deg, bsum);
  kB_scan<<<1, 256, 0, stream>>>(bsum, boff);
  kC_offs<<<196, 256, 0, stream>>>(deg, boff, offs);
  k_scatter<<<3125, 256, 0, stream>>>(ei, offs, cur, perm);
  k1_node_pre<<<3125, 256, 0, stream>>>(x, W1nf, Pb);
  k2_edge<<<12500, 256, 0, stream>>>(Pb, edge_attr, pos, ei, perm, W1ef, W2f,
                                     b1, ln1g, ln1b, sums);
  k3_gru<<<3125, 256, 0, stream>>>(x, sums, deg, Wihf, Whhf, bih, bhh, b2,
                                   ln2g, ln2b, out);
}

// Round 7
// 338.607 us; speedup vs baseline: 1.0958x; 1.0198x over previous
//
#include <hip/hip_runtime.h>
#include <math.h>

#define NN 50000
#define EE 800000

typedef __attribute__((ext_vector_type(8))) short bf16x8;
typedef __attribute__((ext_vector_type(4))) float f32x4;

__device__ __forceinline__ float bf2f(unsigned int h16) {
  union { unsigned u; float f; } z; z.u = h16 << 16; return z.f;
}
__device__ __forceinline__ float uasf(unsigned u) {
  union { unsigned u; float f; } z; z.u = u; return z.f;
}
__device__ __forceinline__ unsigned cvtpk(float lo, float hi) {
  unsigned r;
  asm("v_cvt_pk_bf16_f32 %0, %1, %2" : "=v"(r) : "v"(lo), "v"(hi));
  return r;
}
__device__ __forceinline__ float sigm(float v) { return 1.0f / (1.0f + __expf(-v)); }

__device__ __forceinline__ bf16x8 pack8(float a0, float a1, float a2, float a3,
                                        float a4, float a5, float a6, float a7) {
  union { unsigned u[4]; bf16x8 v; } z;
  z.u[0] = cvtpk(a0, a1); z.u[1] = cvtpk(a2, a3);
  z.u[2] = cvtpk(a4, a5); z.u[3] = cvtpk(a6, a7);
  return z.v;
}

// ============ K0: pack all weights into bf16 MFMA A-fragments ============
__global__ __launch_bounds__(64) void k0_prep(const float* __restrict__ W1,
                                              const float* __restrict__ W2,
                                              const float* __restrict__ Wih,
                                              const float* __restrict__ Whh,
                                              unsigned short* __restrict__ frags) {
  const int f = blockIdx.x, l = threadIdx.x;
  const int c16 = l & 15, kg = l >> 4;
  float v[8];
  if (f < 8) {
    const int c = f * 16 + c16;
#pragma unroll
    for (int j = 0; j < 8; ++j) {
      const int k = kg * 8 + j;
      v[j] = (k < 20) ? W1[(256 + k) * 128 + c] : 0.0f;
    }
  } else if (f < 40) {
    const int lf = f - 8, ct = lf >> 2, ks = lf & 3, c = ct * 16 + c16;
#pragma unroll
    for (int j = 0; j < 8; ++j) { const int k = ks * 32 + kg * 8 + j; v[j] = W2[k * 128 + c]; }
  } else if (f < 104) {
    const int lf = f - 40, ct = lf >> 2, ks = lf & 3, c = ct * 16 + c16;
#pragma unroll
    for (int j = 0; j < 8; ++j) {
      const int k = ks * 32 + kg * 8 + j;
      v[j] = (c < 128) ? W1[k * 128 + c] : W1[(128 + k) * 128 + (c - 128)];
    }
  } else if (f < 200) {
    const int lf = f - 104, ct = lf >> 2, ks = lf & 3, c = ct * 16 + c16;
#pragma unroll
    for (int j = 0; j < 8; ++j) { const int k = ks * 32 + kg * 8 + j; v[j] = Wih[c * 128 + k]; }
  } else {
    const int lf = f - 200, ct = lf >> 2, ks = lf & 3, c = ct * 16 + c16;
#pragma unroll
    for (int j = 0; j < 8; ++j) { const int k = ks * 32 + kg * 8 + j; v[j] = Whh[c * 128 + k]; }
  }
  *(bf16x8*)(frags + (size_t)f * 512 + l * 8) =
      pack8(v[0], v[1], v[2], v[3], v[4], v[5], v[6], v[7]);
}

// ============ counting sort of edges by dst ============
__global__ __launch_bounds__(256) void k_hist(const int* __restrict__ ei,
                                              int* __restrict__ deg) {
  const int e = blockIdx.x * 256 + threadIdx.x;
  if (e < EE) atomicAdd(&deg[ei[EE + e]], 1);
}

__global__ __launch_bounds__(256) void kA_partial(const int* __restrict__ deg,
                                                  int* __restrict__ bsum) {
  const int i = blockIdx.x * 256 + threadIdx.x;
  int v = (i < NN) ? deg[i] : 0;
#pragma unroll
  for (int o = 32; o > 0; o >>= 1) v += __shfl_down(v, o);
  __shared__ int wsum[4];
  if ((threadIdx.x & 63) == 0) wsum[threadIdx.x >> 6] = v;
  __syncthreads();
  if (threadIdx.x == 0) bsum[blockIdx.x] = wsum[0] + wsum[1] + wsum[2] + wsum[3];
}

__global__ __launch_bounds__(256) void kB_scan(const int* __restrict__ bsum,
                                               int* __restrict__ boff) {
  __shared__ int s[256];
  const int t = threadIdx.x;
  const int orig = (t < 196) ? bsum[t] : 0;
  s[t] = orig;
  __syncthreads();
  for (int o = 1; o < 256; o <<= 1) {
    const int v = (t >= o) ? s[t - o] : 0;
    __syncthreads();
    s[t] += v;
    __syncthreads();
  }
  if (t < 196) boff[t] = s[t] - orig;
}

__global__ __launch_bounds__(256) void kC_offs(const int* __restrict__ deg,
                                               const int* __restrict__ boff,
                                               int* __restrict__ offs) {
  __shared__ int s[256];
  const int t = threadIdx.x, i = blockIdx.x * 256 + t;
  const int orig = (i < NN) ? deg[i] : 0;
  s[t] = orig;
  __syncthreads();
  for (int o = 1; o < 256; o <<= 1) {
    const int v = (t >= o) ? s[t - o] : 0;
    __syncthreads();
    s[t] += v;
    __syncthreads();
  }
  if (i < NN) offs[i] = boff[blockIdx.x] + s[t] - orig;
}

__global__ __launch_bounds__(256) void k_scatter(const int* __restrict__ ei,
                                                 const int* __restrict__ offs,
                                                 int* __restrict__ cur,
                                                 int* __restrict__ perm) {
  const int e = blockIdx.x * 256 + threadIdx.x;
  if (e < EE) {
    const int d = ei[EE + e];
    const int p = atomicAdd(&cur[d], 1);
    perm[offs[d] + p] = e;
  }
}

// ============ K1: P = x @ [W1_dst | W1_src], fragment-grouped layout ============
// P[node][kg*64 + half*32 + C4*4 + j]  (C = col/16, half = C>>3, C4 = C&7)
__global__ __launch_bounds__(256) void k1_node_pre(const float* __restrict__ x,
                                                   const unsigned short* __restrict__ W1nf,
                                                   unsigned short* __restrict__ P) {
  const int t = threadIdx.x, lane = t & 63, w = t >> 6;
  const int kg = lane >> 4, li = lane & 15;
  const int node = blockIdx.x * 16 + li;   // 3125*16 = 50000 exact
  const f32x4 zf = {0.0f, 0.0f, 0.0f, 0.0f};
  f32x4 acc[4] = {zf, zf, zf, zf};
#pragma unroll
  for (int ks = 0; ks < 4; ++ks) {
    const float* xp = x + (size_t)node * 128 + ks * 32 + kg * 8;
    const float4 u = *(const float4*)xp, v = *(const float4*)(xp + 4);
    const bf16x8 xb = pack8(u.x, u.y, u.z, u.w, v.x, v.y, v.z, v.w);
#pragma unroll
    for (int i = 0; i < 4; ++i) {
      const int ct = w * 4 + i;
      const bf16x8 af = *(const bf16x8*)(W1nf + (size_t)(ct * 4 + ks) * 512 + lane * 8);
      acc[i] = __builtin_amdgcn_mfma_f32_16x16x32_bf16(af, xb, acc[i], 0, 0, 0);
    }
  }
#pragma unroll
  for (int i = 0; i < 4; ++i) {
    const int C = w * 4 + i;                                  // 0..15
    const int off = kg * 64 + ((C >> 3) * 32) + ((C & 7) * 4);
    *(uint2*)(P + (size_t)node * 256 + off) =
        make_uint2(cvtpk(acc[i][0], acc[i][1]), cvtpk(acc[i][2], acc[i][3]));
  }
}

// ============ K2: fused edge kernel — fragment-resident A-path, 2 barriers ============
__global__ __launch_bounds__(256) void k2_edge(const unsigned short* __restrict__ P,
                                               const float* __restrict__ edge_attr,
                                               const float* __restrict__ pos,
                                               const int* __restrict__ ei,
                                               const int* __restrict__ perm,
                                               const unsigned short* __restrict__ W1ef,
                                               const unsigned short* __restrict__ W2f,
                                               const float* __restrict__ b1,
                                               const float* __restrict__ ln1g,
                                               const float* __restrict__ ln1b,
                                               float* __restrict__ sums) {
  __shared__ __align__(16) unsigned short htile[64][136];  // h (bf16), then msg in place
  __shared__ __align__(16) float4 relv[64];
  __shared__ int dsts[64], srcs[64], eids[64];
  __shared__ __align__(16) float b1s[128];
  __shared__ __align__(16) float g1s[128];
  __shared__ __align__(16) float bb1s[128];

  const int t = threadIdx.x, lane = t & 63, w = t >> 6;
  const int kg = lane >> 4, li = lane & 15;
  const int e0 = blockIdx.x * 64;   // 12500*64 = 800000 exact
  const int el = w * 16 + li;       // this lane's edge row

  if (t < 128) { b1s[t] = b1[t]; g1s[t] = ln1g[t]; bb1s[t] = ln1b[t]; }
  if (t < 64) {
    const int e = perm[e0 + t];
    eids[t] = e;
    const int s = ei[e], d = ei[EE + e];
    srcs[t] = s; dsts[t] = d;
    const float rx = (pos[3 * s + 0] - pos[3 * d + 0]) * 0.2f;
    const float ry = (pos[3 * s + 1] - pos[3 * d + 1]) * 0.2f;
    const float rz = (pos[3 * s + 2] - pos[3 * d + 2]) * 0.2f;
    relv[t] = make_float4(rx, ry, rz, rx * rx + ry * ry + rz * rz);
  }
  __syncthreads();   // barrier 1

  // ---- fragment-layout P gathers, 16B/lane coalesced, issued early ----
  const int dn = dsts[el], sn = srcs[el];
  const uint4* pdp = (const uint4*)(P + (size_t)dn * 256 + kg * 64);
  const uint4* psp = (const uint4*)(P + (size_t)sn * 256 + kg * 64 + 32);
  uint4 PV[4] = {pdp[0], pdp[1], pdp[2], pdp[3]};
  uint4 SV[4] = {psp[0], psp[1], psp[2], psp[3]};

  // ---- A1: acc = (ea|geom) @ W1[256:276] + b1 (b1 as C operand) ----
  bf16x8 bfrag;
  if (kg < 2) {
    const float* ep = edge_attr + (size_t)eids[el] * 16 + kg * 8;
    const float4 u = *(const float4*)ep, v = *(const float4*)(ep + 4);
    bfrag = pack8(u.x, u.y, u.z, u.w, v.x, v.y, v.z, v.w);
  } else if (kg == 2) {
    const float4 rv = relv[el];
    bfrag = pack8(rv.x, rv.y, rv.z, rv.w, 0.f, 0.f, 0.f, 0.f);
  } else {
    bfrag = pack8(0.f, 0.f, 0.f, 0.f, 0.f, 0.f, 0.f, 0.f);
  }
  f32x4 acc[8];
#pragma unroll
  for (int cf = 0; cf < 8; ++cf) {
    const f32x4 bC = *(const f32x4*)&b1s[cf * 16 + kg * 4];
    const bf16x8 af = *(const bf16x8*)(W1ef + (size_t)cf * 512 + lane * 8);
    acc[cf] = __builtin_amdgcn_mfma_f32_16x16x32_bf16(af, bfrag, bC, 0, 0, 0);
  }

  // ---- A2: acc += Pd + Ps ; LN over 128 (2 shfls) ; SiLU ; write h once ----
  float s1 = 0.0f, s2 = 0.0f;
#pragma unroll
  for (int q = 0; q < 4; ++q) {
    const unsigned pdx[4] = {PV[q].x, PV[q].y, PV[q].z, PV[q].w};
    const unsigned psx[4] = {SV[q].x, SV[q].y, SV[q].z, SV[q].w};
#pragma unroll
    for (int h2 = 0; h2 < 4; ++h2) {
      const int cf = 2 * q + (h2 >> 1);
      const int j0 = (h2 & 1) * 2;
      const float a0 = uasf(pdx[h2] << 16) + uasf(psx[h2] << 16);
      const float a1 = uasf(pdx[h2] & 0xffff0000u) + uasf(psx[h2] & 0xffff0000u);
      const float v0 = acc[cf][j0] + a0;
      const float v1 = acc[cf][j0 + 1] + a1;
      acc[cf][j0] = v0; acc[cf][j0 + 1] = v1;
      s1 += v0 + v1; s2 += v0 * v0 + v1 * v1;
    }
  }
  s1 += __shfl_xor(s1, 16); s2 += __shfl_xor(s2, 16);
  s1 += __shfl_xor(s1, 32); s2 += __shfl_xor(s2, 32);
  const float m = s1 * (1.0f / 128.0f);
  const float var = s2 * (1.0f / 128.0f) - m * m;
  const float rstd = rsqrtf(var + 1e-5f);
#pragma unroll
  for (int cf = 0; cf < 8; ++cf) {
    const f32x4 gg = *(const f32x4*)&g1s[cf * 16 + kg * 4];
    const f32x4 be = *(const f32x4*)&bb1s[cf * 16 + kg * 4];
    float y0 = gg[0] * ((acc[cf][0] - m) * rstd) + be[0];
    float y1 = gg[1] * ((acc[cf][1] - m) * rstd) + be[1];
    float y2 = gg[2] * ((acc[cf][2] - m) * rstd) + be[2];
    float y3 = gg[3] * ((acc[cf][3] - m) * rstd) + be[3];
    y0 *= sigm(y0); y1 *= sigm(y1); y2 *= sigm(y2); y3 *= sigm(y3);
    *(uint2*)&htile[el][cf * 16 + kg * 4] = make_uint2(cvtpk(y0, y1), cvtpk(y2, y3));
  }

  // intra-wave LDS ordering (wave's writes land before its cross-lane reads)
  asm volatile("s_waitcnt lgkmcnt(0)" ::: "memory");
  __builtin_amdgcn_sched_barrier(0);

  // ---- B: msg^T = W2^T x h (own rows only), write msg back in place ----
  {
    bf16x8 hfr[4];
#pragma unroll
    for (int ks = 0; ks < 4; ++ks)
      hfr[ks] = *(const bf16x8*)&htile[el][ks * 32 + kg * 8];

    const f32x4 zf = {0.0f, 0.0f, 0.0f, 0.0f};
    f32x4 macc[8];
#pragma unroll
    for (int cf = 0; cf < 8; ++cf) macc[cf] = zf;
#pragma unroll
    for (int ks = 0; ks < 4; ++ks) {
#pragma unroll
      for (int cf = 0; cf < 8; ++cf) {
        const bf16x8 wf = *(const bf16x8*)(W2f + (size_t)((cf << 2) | ks) * 512 + lane * 8);
        macc[cf] = __builtin_amdgcn_mfma_f32_16x16x32_bf16(wf, hfr[ks], macc[cf], 0, 0, 0);
      }
    }
#pragma unroll
    for (int cf = 0; cf < 8; ++cf) {
      *(uint2*)&htile[el][cf * 16 + kg * 4] =
          make_uint2(cvtpk(macc[cf][0], macc[cf][1]), cvtpk(macc[cf][2], macc[cf][3]));
    }
  }
  __syncthreads();   // barrier 2

  // ---- C: segmented-run reduction over sorted dsts, coalesced flush ----
  {
    const int c = t & 127;            // column
    const int h0 = (t >> 7) * 32;     // edges h0..h0+31 (wave-uniform)
    int rd = dsts[h0];
    float racc = bf2f((unsigned)htile[h0][c]);
#pragma unroll
    for (int i = 1; i < 32; ++i) {
      const int ee = h0 + i;
      const int d = dsts[ee];
      const float v = bf2f((unsigned)htile[ee][c]);
      if (d == rd) {
        racc += v;
      } else {
        atomicAdd(sums + (size_t)rd * 128 + c, racc);
        rd = d; racc = v;
      }
    }
    atomicAdd(sums + (size_t)rd * 128 + c, racc);
  }
}

// ============ K3: GRU + LN2 (MFMA), 16 nodes per block ============
__global__ __launch_bounds__(256) void k3_gru(const float* __restrict__ x,
                                              const float* __restrict__ sums,
                                              const int* __restrict__ deg,
                                              const unsigned short* __restrict__ Wihf,
                                              const unsigned short* __restrict__ Whhf,
                                              const float* __restrict__ bih,
                                              const float* __restrict__ bhh,
                                              const float* __restrict__ b2,
                                              const float* __restrict__ ln2g,
                                              const float* __restrict__ ln2b,
                                              float* __restrict__ out) {
  __shared__ unsigned short aggb[16][136];   // agg bf16
  __shared__ unsigned short Ss[16][776];     // [gi(384) | gh(384)] bf16
  const int t = threadIdx.x, lane = t & 63, w = t >> 6;
  const int kg = lane >> 4, li = lane & 15;
  const int n0 = blockIdx.x * 16;   // 3125*16 = 50000 exact

  // stage agg = sums/max(deg,1) + (deg>0)*b2
  {
    const int nl = t >> 4, c0 = (t & 15) * 8;
    const int gn = n0 + nl;
    const int dc = deg[gn];
    const float inv = 1.0f / fmaxf((float)dc, 1.0f);
    const float bsc = (dc > 0) ? 1.0f : 0.0f;
    const float* sp = sums + (size_t)gn * 128 + c0;
    const float4 u = *(const float4*)sp, v = *(const float4*)(sp + 4);
    const float4 bu = *(const float4*)(b2 + c0), bv = *(const float4*)(b2 + c0 + 4);
    const unsigned o0 = cvtpk(u.x * inv + bsc * bu.x, u.y * inv + bsc * bu.y);
    const unsigned o1 = cvtpk(u.z * inv + bsc * bu.z, u.w * inv + bsc * bu.w);
    const unsigned o2 = cvtpk(v.x * inv + bsc * bv.x, v.y * inv + bsc * bv.y);
    const unsigned o3 = cvtpk(v.z * inv + bsc * bv.z, v.w * inv + bsc * bv.w);
    *(uint4*)&aggb[nl][c0] = make_uint4(o0, o1, o2, o3);
  }
  __syncthreads();

  // waves 0-1: gi = agg@Wih^T ; waves 2-3: gh = x@Whh^T
  const int isH = w >> 1;
  const int ctbase = (w & 1) * 12;
  const unsigned short* Wf = isH ? Whhf : Wihf;
  const float* bias = isH ? bhh : bih;
  const f32x4 zf = {0.0f, 0.0f, 0.0f, 0.0f};
  f32x4 acc[12];
#pragma unroll
  for (int i = 0; i < 12; ++i) acc[i] = zf;
#pragma unroll
  for (int ks = 0; ks < 4; ++ks) {
    bf16x8 bfrag;
    if (isH) {
      const float* xp = x + (size_t)(n0 + li) * 128 + ks * 32 + kg * 8;
      const float4 u = *(const float4*)xp, v = *(const float4*)(xp + 4);
      bfrag = pack8(u.x, u.y, u.z, u.w, v.x, v.y, v.z, v.w);
    } else {
      bfrag = *(const bf16x8*)&aggb[li][ks * 32 + kg * 8];
    }
#pragma unroll
    for (int i = 0; i < 12; ++i) {
      const int ct = ctbase + i;
      const bf16x8 af = *(const bf16x8*)(Wf + (size_t)(ct * 4 + ks) * 512 + lane * 8);
      acc[i] = __builtin_amdgcn_mfma_f32_16x16x32_bf16(af, bfrag, acc[i], 0, 0, 0);
    }
  }
#pragma unroll
  for (int i = 0; i < 12; ++i) {
    const int ocol = (ctbase + i) * 16 + kg * 4;
    const float4 bb = *(const float4*)(bias + ocol);
    const int col = isH * 384 + ocol;
    const unsigned lo = cvtpk(acc[i][0] + bb.x, acc[i][1] + bb.y);
    const unsigned hi = cvtpk(acc[i][2] + bb.z, acc[i][3] + bb.w);
    *(uint2*)&Ss[li][col] = make_uint2(lo, hi);
  }
  __syncthreads();

  // gates + residual + LN2
  const int nl = t >> 4, q0 = (t & 15) * 8;
  const int gn = n0 + nl;
  float xv[8];
  *(float4*)&xv[0] = *(const float4*)(x + (size_t)gn * 128 + q0);
  *(float4*)&xv[4] = *(const float4*)(x + (size_t)gn * 128 + q0 + 4);
  const uint4 gir = *(const uint4*)&Ss[nl][q0];
  const uint4 giz = *(const uint4*)&Ss[nl][q0 + 128];
  const uint4 gin = *(const uint4*)&Ss[nl][q0 + 256];
  const uint4 ghr = *(const uint4*)&Ss[nl][q0 + 384];
  const uint4 ghz = *(const uint4*)&Ss[nl][q0 + 512];
  const uint4 ghn = *(const uint4*)&Ss[nl][q0 + 640];
  const unsigned GIR[4] = {gir.x, gir.y, gir.z, gir.w};
  const unsigned GIZ[4] = {giz.x, giz.y, giz.z, giz.w};
  const unsigned GIN[4] = {gin.x, gin.y, gin.z, gin.w};
  const unsigned GHR[4] = {ghr.x, ghr.y, ghr.z, ghr.w};
  const unsigned GHZ[4] = {ghz.x, ghz.y, ghz.z, ghz.w};
  const unsigned GHN[4] = {ghn.x, ghn.y, ghn.z, ghn.w};
  float vb[8];
  float s1 = 0.0f, s2 = 0.0f;
#pragma unroll
  for (int j2 = 0; j2 < 4; ++j2) {
#pragma unroll
    for (int hl = 0; hl < 2; ++hl) {
      const int jj = j2 * 2 + hl;
      const unsigned sh = hl * 16;
      const float girv = bf2f((GIR[j2] >> sh) & 0xffffu);
      const float gizv = bf2f((GIZ[j2] >> sh) & 0xffffu);
      const float ginv = bf2f((GIN[j2] >> sh) & 0xffffu);
      const float ghrv = bf2f((GHR[j2] >> sh) & 0xffffu);
      const float ghzv = bf2f((GHZ[j2] >> sh) & 0xffffu);
      const float ghnv = bf2f((GHN[j2] >> sh) & 0xffffu);
      const float r = sigm(girv + ghrv);
      const float z = sigm(gizv + ghzv);
      const float nv = tanhf(ginv + r * ghnv);
      const float v = xv[jj] + (1.0f - z) * nv + z * xv[jj];
      vb[jj] = v; s1 += v; s2 += v * v;
    }
  }
  s1 += __shfl_xor(s1, 1); s2 += __shfl_xor(s2, 1);
  s1 += __shfl_xor(s1, 2); s2 += __shfl_xor(s2, 2);
  s1 += __shfl_xor(s1, 4); s2 += __shfl_xor(s2, 4);
  s1 += __shfl_xor(s1, 8); s2 += __shfl_xor(s2, 8);
  const float m = s1 * (1.0f / 128.0f);
  const float var = s2 * (1.0f / 128.0f) - m * m;
  const float rstd = rsqrtf(var + 1e-5f);
  float ov[8];
#pragma unroll
  for (int j = 0; j < 8; ++j)
    ov[j] = ln2g[q0 + j] * ((vb[j] - m) * rstd) + ln2b[q0 + j];
  *(float4*)(out + (size_t)gn * 128 + q0) = make_float4(ov[0], ov[1], ov[2], ov[3]);
  *(float4*)(out + (size_t)gn * 128 + q0 + 4) = make_float4(ov[4], ov[5], ov[6], ov[7]);
}

extern "C" void kernel_launch(void* const* d_in, const int* in_sizes, int n_in,
                              void* d_out, int out_size, void* d_ws, size_t ws_size,
                              hipStream_t stream) {
  const float* x         = (const float*)d_in[0];
  const float* edge_attr = (const float*)d_in[1];
  const float* pos       = (const float*)d_in[2];
  const float* W1        = (const float*)d_in[3];
  const float* b1        = (const float*)d_in[4];
  const float* ln1g      = (const float*)d_in[5];
  const float* ln1b      = (const float*)d_in[6];
  const float* W2        = (const float*)d_in[7];
  const float* b2        = (const float*)d_in[8];
  const float* Wih       = (const float*)d_in[9];
  const float* bih       = (const float*)d_in[10];
  const float* Whh       = (const float*)d_in[11];
  const float* bhh       = (const float*)d_in[12];
  const float* ln2g      = (const float*)d_in[13];
  const float* ln2b      = (const float*)d_in[14];
  const int*   ei        = (const int*)d_in[15];
  float* out = (float*)d_out;

  // ws layout (bytes)
  float*          sums  = (float*)d_ws;                                   // 25,600,000
  unsigned short* Pb    = (unsigned short*)((char*)d_ws + 25600000);      // 25,600,000
  unsigned short* frags = (unsigned short*)((char*)d_ws + 51200000);      //    303,104
  int*            deg   = (int*)((char*)d_ws + 51600000);                 //    200,000
  int*            cur   = (int*)((char*)d_ws + 51800000);                 //    200,000
  int*            offs  = (int*)((char*)d_ws + 52000000);                 //    200,000
  int*            bsum  = (int*)((char*)d_ws + 52200000);                 //        784
  int*            boff  = (int*)((char*)d_ws + 52204096);                 //        784
  int*            perm  = (int*)((char*)d_ws + 52300000);                 //  3,200,000
  unsigned short* W1ef = frags;               // 8 frags
  unsigned short* W2f  = frags + 8 * 512;     // 32 frags
  unsigned short* W1nf = frags + 40 * 512;    // 64 frags
  unsigned short* Wihf = frags + 104 * 512;   // 96 frags
  unsigned short* Whhf = frags + 200 * 512;   // 96 frags

  hipMemsetAsync(sums, 0, (size_t)NN * 128 * sizeof(float), stream);
  hipMemsetAsync(deg, 0, 2 * 200000, stream);   // deg + cur

  k0_prep<<<296, 64, 0, stream>>>(W1, W2, Wih, Whh, frags);
  k_hist<<<3125, 256, 0, stream>>>(ei, deg);
  kA_partial<<<196, 256, 0, stream>>>(deg, bsum);
  kB_scan<<<1, 256, 0, stream>>>(bsum, boff);
  kC_offs<<<196, 256, 0, stream>>>(deg, boff, offs);
  k_scatter<<<3125, 256, 0, stream>>>(ei, offs, cur, perm);
  k1_node_pre<<<3125, 256, 0, stream>>>(x, W1nf, Pb);
  k2_edge<<<12500, 256, 0, stream>>>(Pb, edge_attr, pos, ei, perm, W1ef, W2f,
                                     b1, ln1g, ln1b, sums);
  k3_gru<<<3125, 256, 0, stream>>>(x, sums, deg, Wihf, Whhf, bih, bhh, b2,
                                   ln2g, ln2b, out);
}

// Round 8
// 325.524 us; speedup vs baseline: 1.1399x; 1.0402x over previous
//
#include <hip/hip_runtime.h>
#include <math.h>

#define NN 50000
#define EE 800000

typedef __attribute__((ext_vector_type(8))) short bf16x8;
typedef __attribute__((ext_vector_type(4))) float f32x4;

__device__ __forceinline__ float bf2f(unsigned int h16) {
  union { unsigned u; float f; } z; z.u = h16 << 16; return z.f;
}
__device__ __forceinline__ float uasf(unsigned u) {
  union { unsigned u; float f; } z; z.u = u; return z.f;
}
__device__ __forceinline__ unsigned cvtpk(float lo, float hi) {
  unsigned r;
  asm("v_cvt_pk_bf16_f32 %0, %1, %2" : "=v"(r) : "v"(lo), "v"(hi));
  return r;
}
__device__ __forceinline__ float sigm(float v) { return 1.0f / (1.0f + __expf(-v)); }

__device__ __forceinline__ bf16x8 pack8(float a0, float a1, float a2, float a3,
                                        float a4, float a5, float a6, float a7) {
  union { unsigned u[4]; bf16x8 v; } z;
  z.u[0] = cvtpk(a0, a1); z.u[1] = cvtpk(a2, a3);
  z.u[2] = cvtpk(a4, a5); z.u[3] = cvtpk(a6, a7);
  return z.v;
}

// ============ K0: pack all weights into bf16 MFMA A-fragments ============
__global__ __launch_bounds__(64) void k0_prep(const float* __restrict__ W1,
                                              const float* __restrict__ W2,
                                              const float* __restrict__ Wih,
                                              const float* __restrict__ Whh,
                                              unsigned short* __restrict__ frags) {
  const int f = blockIdx.x, l = threadIdx.x;
  const int c16 = l & 15, kg = l >> 4;
  float v[8];
  if (f < 8) {
    const int c = f * 16 + c16;
#pragma unroll
    for (int j = 0; j < 8; ++j) {
      const int k = kg * 8 + j;
      v[j] = (k < 20) ? W1[(256 + k) * 128 + c] : 0.0f;
    }
  } else if (f < 40) {
    const int lf = f - 8, ct = lf >> 2, ks = lf & 3, c = ct * 16 + c16;
#pragma unroll
    for (int j = 0; j < 8; ++j) { const int k = ks * 32 + kg * 8 + j; v[j] = W2[k * 128 + c]; }
  } else if (f < 104) {
    const int lf = f - 40, ct = lf >> 2, ks = lf & 3, c = ct * 16 + c16;
#pragma unroll
    for (int j = 0; j < 8; ++j) {
      const int k = ks * 32 + kg * 8 + j;
      v[j] = (c < 128) ? W1[k * 128 + c] : W1[(128 + k) * 128 + (c - 128)];
    }
  } else if (f < 200) {
    const int lf = f - 104, ct = lf >> 2, ks = lf & 3, c = ct * 16 + c16;
#pragma unroll
    for (int j = 0; j < 8; ++j) { const int k = ks * 32 + kg * 8 + j; v[j] = Wih[c * 128 + k]; }
  } else {
    const int lf = f - 200, ct = lf >> 2, ks = lf & 3, c = ct * 16 + c16;
#pragma unroll
    for (int j = 0; j < 8; ++j) { const int k = ks * 32 + kg * 8 + j; v[j] = Whh[c * 128 + k]; }
  }
  *(bf16x8*)(frags + (size_t)f * 512 + l * 8) =
      pack8(v[0], v[1], v[2], v[3], v[4], v[5], v[6], v[7]);
}

// ============ counting sort of edges by dst ============
__global__ __launch_bounds__(256) void k_hist(const int* __restrict__ ei,
                                              int* __restrict__ deg) {
  const int e = blockIdx.x * 256 + threadIdx.x;
  if (e < EE) atomicAdd(&deg[ei[EE + e]], 1);
}

__global__ __launch_bounds__(256) void kA_partial(const int* __restrict__ deg,
                                                  int* __restrict__ bsum) {
  const int i = blockIdx.x * 256 + threadIdx.x;
  int v = (i < NN) ? deg[i] : 0;
#pragma unroll
  for (int o = 32; o > 0; o >>= 1) v += __shfl_down(v, o);
  __shared__ int wsum[4];
  if ((threadIdx.x & 63) == 0) wsum[threadIdx.x >> 6] = v;
  __syncthreads();
  if (threadIdx.x == 0) bsum[blockIdx.x] = wsum[0] + wsum[1] + wsum[2] + wsum[3];
}

__global__ __launch_bounds__(256) void kB_scan(const int* __restrict__ bsum,
                                               int* __restrict__ boff) {
  __shared__ int s[256];
  const int t = threadIdx.x;
  const int orig = (t < 196) ? bsum[t] : 0;
  s[t] = orig;
  __syncthreads();
  for (int o = 1; o < 256; o <<= 1) {
    const int v = (t >= o) ? s[t - o] : 0;
    __syncthreads();
    s[t] += v;
    __syncthreads();
  }
  if (t < 196) boff[t] = s[t] - orig;
}

__global__ __launch_bounds__(256) void kC_offs(const int* __restrict__ deg,
                                               const int* __restrict__ boff,
                                               int* __restrict__ offs) {
  __shared__ int s[256];
  const int t = threadIdx.x, i = blockIdx.x * 256 + t;
  const int orig = (i < NN) ? deg[i] : 0;
  s[t] = orig;
  __syncthreads();
  for (int o = 1; o < 256; o <<= 1) {
    const int v = (t >= o) ? s[t - o] : 0;
    __syncthreads();
    s[t] += v;
    __syncthreads();
  }
  if (i < NN) offs[i] = boff[blockIdx.x] + s[t] - orig;
}

__global__ __launch_bounds__(256) void k_scatter(const int* __restrict__ ei,
                                                 const int* __restrict__ offs,
                                                 int* __restrict__ cur,
                                                 int* __restrict__ perm) {
  const int e = blockIdx.x * 256 + threadIdx.x;
  if (e < EE) {
    const int d = ei[EE + e];
    const int p = atomicAdd(&cur[d], 1);
    perm[offs[d] + p] = e;
  }
}

// ============ K1: Pd = x@W1_dst, Ps = x@W1_src — frag-grouped, split arrays ============
// Pd[node][kg*32 + C*4 + j]  (C = outcol/16 in 0..7)
__global__ __launch_bounds__(256) void k1_node_pre(const float* __restrict__ x,
                                                   const unsigned short* __restrict__ W1nf,
                                                   unsigned short* __restrict__ Pd,
                                                   unsigned short* __restrict__ Ps) {
  const int t = threadIdx.x, lane = t & 63, w = t >> 6;
  const int kg = lane >> 4, li = lane & 15;
  const int node = blockIdx.x * 16 + li;   // 3125*16 = 50000 exact
  const f32x4 zf = {0.0f, 0.0f, 0.0f, 0.0f};
  f32x4 acc[4] = {zf, zf, zf, zf};
#pragma unroll
  for (int ks = 0; ks < 4; ++ks) {
    const float* xp = x + (size_t)node * 128 + ks * 32 + kg * 8;
    const float4 u = *(const float4*)xp, v = *(const float4*)(xp + 4);
    const bf16x8 xb = pack8(u.x, u.y, u.z, u.w, v.x, v.y, v.z, v.w);
#pragma unroll
    for (int i = 0; i < 4; ++i) {
      const int ct = w * 4 + i;
      const bf16x8 af = *(const bf16x8*)(W1nf + (size_t)(ct * 4 + ks) * 512 + lane * 8);
      acc[i] = __builtin_amdgcn_mfma_f32_16x16x32_bf16(af, xb, acc[i], 0, 0, 0);
    }
  }
#pragma unroll
  for (int i = 0; i < 4; ++i) {
    const int C = w * 4 + i;                         // 0..15
    unsigned short* base = (C < 8) ? Pd : Ps;
    const int off = kg * 32 + (C & 7) * 4;
    *(uint2*)(base + (size_t)node * 128 + off) =
        make_uint2(cvtpk(acc[i][0], acc[i][1]), cvtpk(acc[i][2], acc[i][3]));
  }
}

// ============ K2: fused edge kernel — split-P gathers + run-table scatter ============
__global__ __launch_bounds__(256) void k2_edge(const unsigned short* __restrict__ Pd,
                                               const unsigned short* __restrict__ Ps,
                                               const float* __restrict__ edge_attr,
                                               const float* __restrict__ pos,
                                               const int* __restrict__ ei,
                                               const int* __restrict__ perm,
                                               const unsigned short* __restrict__ W1ef,
                                               const unsigned short* __restrict__ W2f,
                                               const float* __restrict__ b1,
                                               const float* __restrict__ ln1g,
                                               const float* __restrict__ ln1b,
                                               float* __restrict__ sums) {
  __shared__ __align__(16) unsigned short htile[64][136];  // h (bf16), then msg in place
  __shared__ __align__(16) float4 relv[64];
  __shared__ int dsts[64], srcs[64], eids[64];
  __shared__ int runStart[65];
  __shared__ int runCnt;
  __shared__ __align__(16) float b1s[128];
  __shared__ __align__(16) float g1s[128];
  __shared__ __align__(16) float bb1s[128];

  const int t = threadIdx.x, lane = t & 63, w = t >> 6;
  const int kg = lane >> 4, li = lane & 15;
  const int e0 = blockIdx.x * 64;   // 12500*64 = 800000 exact
  const int el = w * 16 + li;       // this lane's edge row

  if (t < 128) { b1s[t] = b1[t]; g1s[t] = ln1g[t]; bb1s[t] = ln1b[t]; }
  if (t < 64) {
    const int e = perm[e0 + t];
    eids[t] = e;
    const int s = ei[e], d = ei[EE + e];
    srcs[t] = s; dsts[t] = d;
    const float rx = (pos[3 * s + 0] - pos[3 * d + 0]) * 0.2f;
    const float ry = (pos[3 * s + 1] - pos[3 * d + 1]) * 0.2f;
    const float rz = (pos[3 * s + 2] - pos[3 * d + 2]) * 0.2f;
    relv[t] = make_float4(rx, ry, rz, rx * rx + ry * ry + rz * rz);
  }
  __syncthreads();   // barrier 1

  // ---- run table (wave 0 only): ballot over dst-change flags ----
  if (w == 0) {
    const bool flag = (lane == 0) || (dsts[lane] != dsts[lane - 1]);
    const unsigned long long mask = __ballot(flag);
    const int rid = __popcll(mask & ((1ull << lane) - 1ull));
    if (flag) runStart[rid] = lane;
    if (lane == 63) {
      const int nr = __popcll(mask);
      runCnt = nr;
      runStart[nr] = 64;
    }
  }

  // ---- split-P fragment gathers: 64B/lane contiguous, fully used ----
  const int dn = dsts[el], sn = srcs[el];
  const uint4* pdp = (const uint4*)(Pd + (size_t)dn * 128 + kg * 32);
  const uint4* psp = (const uint4*)(Ps + (size_t)sn * 128 + kg * 32);
  uint4 PV[4] = {pdp[0], pdp[1], pdp[2], pdp[3]};
  uint4 SV[4] = {psp[0], psp[1], psp[2], psp[3]};

  // ---- A1: acc = (ea|geom) @ W1[256:276] + b1 (b1 as C operand) ----
  bf16x8 bfrag;
  if (kg < 2) {
    const float* ep = edge_attr + (size_t)eids[el] * 16 + kg * 8;
    const float4 u = *(const float4*)ep, v = *(const float4*)(ep + 4);
    bfrag = pack8(u.x, u.y, u.z, u.w, v.x, v.y, v.z, v.w);
  } else if (kg == 2) {
    const float4 rv = relv[el];
    bfrag = pack8(rv.x, rv.y, rv.z, rv.w, 0.f, 0.f, 0.f, 0.f);
  } else {
    bfrag = pack8(0.f, 0.f, 0.f, 0.f, 0.f, 0.f, 0.f, 0.f);
  }
  f32x4 acc[8];
#pragma unroll
  for (int cf = 0; cf < 8; ++cf) {
    const f32x4 bC = *(const f32x4*)&b1s[cf * 16 + kg * 4];
    const bf16x8 af = *(const bf16x8*)(W1ef + (size_t)cf * 512 + lane * 8);
    acc[cf] = __builtin_amdgcn_mfma_f32_16x16x32_bf16(af, bfrag, bC, 0, 0, 0);
  }

  // ---- A2: acc += Pd + Ps ; LN over 128 (2 shfls) ; SiLU ; write h once ----
  float s1 = 0.0f, s2 = 0.0f;
#pragma unroll
  for (int q = 0; q < 4; ++q) {
    const unsigned pdx[4] = {PV[q].x, PV[q].y, PV[q].z, PV[q].w};
    const unsigned psx[4] = {SV[q].x, SV[q].y, SV[q].z, SV[q].w};
#pragma unroll
    for (int h2 = 0; h2 < 4; ++h2) {
      const int cf = 2 * q + (h2 >> 1);
      const int j0 = (h2 & 1) * 2;
      const float a0 = uasf(pdx[h2] << 16) + uasf(psx[h2] << 16);
      const float a1 = uasf(pdx[h2] & 0xffff0000u) + uasf(psx[h2] & 0xffff0000u);
      const float v0 = acc[cf][j0] + a0;
      const float v1 = acc[cf][j0 + 1] + a1;
      acc[cf][j0] = v0; acc[cf][j0 + 1] = v1;
      s1 += v0 + v1; s2 += v0 * v0 + v1 * v1;
    }
  }
  s1 += __shfl_xor(s1, 16); s2 += __shfl_xor(s2, 16);
  s1 += __shfl_xor(s1, 32); s2 += __shfl_xor(s2, 32);
  const float m = s1 * (1.0f / 128.0f);
  const float var = s2 * (1.0f / 128.0f) - m * m;
  const float rstd = rsqrtf(var + 1e-5f);
#pragma unroll
  for (int cf = 0; cf < 8; ++cf) {
    const f32x4 gg = *(const f32x4*)&g1s[cf * 16 + kg * 4];
    const f32x4 be = *(const f32x4*)&bb1s[cf * 16 + kg * 4];
    float y0 = gg[0] * ((acc[cf][0] - m) * rstd) + be[0];
    float y1 = gg[1] * ((acc[cf][1] - m) * rstd) + be[1];
    float y2 = gg[2] * ((acc[cf][2] - m) * rstd) + be[2];
    float y3 = gg[3] * ((acc[cf][3] - m) * rstd) + be[3];
    y0 *= sigm(y0); y1 *= sigm(y1); y2 *= sigm(y2); y3 *= sigm(y3);
    *(uint2*)&htile[el][cf * 16 + kg * 4] = make_uint2(cvtpk(y0, y1), cvtpk(y2, y3));
  }

  // intra-wave LDS ordering (wave's writes land before its cross-lane reads)
  asm volatile("s_waitcnt lgkmcnt(0)" ::: "memory");
  __builtin_amdgcn_sched_barrier(0);

  // ---- B: msg^T = W2^T x h (own rows only), write msg back in place ----
  {
    bf16x8 hfr[4];
#pragma unroll
    for (int ks = 0; ks < 4; ++ks)
      hfr[ks] = *(const bf16x8*)&htile[el][ks * 32 + kg * 8];

    const f32x4 zf = {0.0f, 0.0f, 0.0f, 0.0f};
    f32x4 macc[8];
#pragma unroll
    for (int cf = 0; cf < 8; ++cf) macc[cf] = zf;
#pragma unroll
    for (int ks = 0; ks < 4; ++ks) {
#pragma unroll
      for (int cf = 0; cf < 8; ++cf) {
        const bf16x8 wf = *(const bf16x8*)(W2f + (size_t)((cf << 2) | ks) * 512 + lane * 8);
        macc[cf] = __builtin_amdgcn_mfma_f32_16x16x32_bf16(wf, hfr[ks], macc[cf], 0, 0, 0);
      }
    }
#pragma unroll
    for (int cf = 0; cf < 8; ++cf) {
      *(uint2*)&htile[el][cf * 16 + kg * 4] =
          make_uint2(cvtpk(macc[cf][0], macc[cf][1]), cvtpk(macc[cf][2], macc[cf][3]));
    }
  }
  __syncthreads();   // barrier 2

  // ---- C: run-table segmented reduce; wave-uniform runs, coalesced atomics ----
  {
    const int nruns = runCnt;
    const int ntasks = nruns << 7;           // nruns * 128 cols
    for (int base = w * 64; base < ntasks; base += 256) {
      const int run = base >> 7;             // wave-uniform
      const int col = (base & 127) + lane;   // 0..63 or 64..127
      const int s    = __builtin_amdgcn_readfirstlane(runStart[run]);
      const int epos = __builtin_amdgcn_readfirstlane(runStart[run + 1]);
      const int dd   = __builtin_amdgcn_readfirstlane(dsts[s]);
      float racc = 0.0f;
      for (int e = s; e < epos; ++e)
        racc += bf2f((unsigned)htile[e][col]);
      atomicAdd(sums + (size_t)dd * 128 + col, racc);
    }
  }
}

// ============ K3: GRU + LN2 (MFMA), 16 nodes per block ============
__global__ __launch_bounds__(256) void k3_gru(const float* __restrict__ x,
                                              const float* __restrict__ sums,
                                              const int* __restrict__ deg,
                                              const unsigned short* __restrict__ Wihf,
                                              const unsigned short* __restrict__ Whhf,
                                              const float* __restrict__ bih,
                                              const float* __restrict__ bhh,
                                              const float* __restrict__ b2,
                                              const float* __restrict__ ln2g,
                                              const float* __restrict__ ln2b,
                                              float* __restrict__ out) {
  __shared__ unsigned short aggb[16][136];   // agg bf16
  __shared__ unsigned short Ss[16][776];     // [gi(384) | gh(384)] bf16
  const int t = threadIdx.x, lane = t & 63, w = t >> 6;
  const int kg = lane >> 4, li = lane & 15;
  const int n0 = blockIdx.x * 16;   // 3125*16 = 50000 exact

  // stage agg = sums/max(deg,1) + (deg>0)*b2
  {
    const int nl = t >> 4, c0 = (t & 15) * 8;
    const int gn = n0 + nl;
    const int dc = deg[gn];
    const float inv = 1.0f / fmaxf((float)dc, 1.0f);
    const float bsc = (dc > 0) ? 1.0f : 0.0f;
    const float* sp = sums + (size_t)gn * 128 + c0;
    const float4 u = *(const float4*)sp, v = *(const float4*)(sp + 4);
    const float4 bu = *(const float4*)(b2 + c0), bv = *(const float4*)(b2 + c0 + 4);
    const unsigned o0 = cvtpk(u.x * inv + bsc * bu.x, u.y * inv + bsc * bu.y);
    const unsigned o1 = cvtpk(u.z * inv + bsc * bu.z, u.w * inv + bsc * bu.w);
    const unsigned o2 = cvtpk(v.x * inv + bsc * bv.x, v.y * inv + bsc * bv.y);
    const unsigned o3 = cvtpk(v.z * inv + bsc * bv.z, v.w * inv + bsc * bv.w);
    *(uint4*)&aggb[nl][c0] = make_uint4(o0, o1, o2, o3);
  }
  __syncthreads();

  // waves 0-1: gi = agg@Wih^T ; waves 2-3: gh = x@Whh^T
  const int isH = w >> 1;
  const int ctbase = (w & 1) * 12;
  const unsigned short* Wf = isH ? Whhf : Wihf;
  const float* bias = isH ? bhh : bih;
  const f32x4 zf = {0.0f, 0.0f, 0.0f, 0.0f};
  f32x4 acc[12];
#pragma unroll
  for (int i = 0; i < 12; ++i) acc[i] = zf;
#pragma unroll
  for (int ks = 0; ks < 4; ++ks) {
    bf16x8 bfrag;
    if (isH) {
      const float* xp = x + (size_t)(n0 + li) * 128 + ks * 32 + kg * 8;
      const float4 u = *(const float4*)xp, v = *(const float4*)(xp + 4);
      bfrag = pack8(u.x, u.y, u.z, u.w, v.x, v.y, v.z, v.w);
    } else {
      bfrag = *(const bf16x8*)&aggb[li][ks * 32 + kg * 8];
    }
#pragma unroll
    for (int i = 0; i < 12; ++i) {
      const int ct = ctbase + i;
      const bf16x8 af = *(const bf16x8*)(Wf + (size_t)(ct * 4 + ks) * 512 + lane * 8);
      acc[i] = __builtin_amdgcn_mfma_f32_16x16x32_bf16(af, bfrag, acc[i], 0, 0, 0);
    }
  }
#pragma unroll
  for (int i = 0; i < 12; ++i) {
    const int ocol = (ctbase + i) * 16 + kg * 4;
    const float4 bb = *(const float4*)(bias + ocol);
    const int col = isH * 384 + ocol;
    const unsigned lo = cvtpk(acc[i][0] + bb.x, acc[i][1] + bb.y);
    const unsigned hi = cvtpk(acc[i][2] + bb.z, acc[i][3] + bb.w);
    *(uint2*)&Ss[li][col] = make_uint2(lo, hi);
  }
  __syncthreads();

  // gates + residual + LN2
  const int nl = t >> 4, q0 = (t & 15) * 8;
  const int gn = n0 + nl;
  float xv[8];
  *(float4*)&xv[0] = *(const float4*)(x + (size_t)gn * 128 + q0);
  *(float4*)&xv[4] = *(const float4*)(x + (size_t)gn * 128 + q0 + 4);
  const uint4 gir = *(const uint4*)&Ss[nl][q0];
  const uint4 giz = *(const uint4*)&Ss[nl][q0 + 128];
  const uint4 gin = *(const uint4*)&Ss[nl][q0 + 256];
  const uint4 ghr = *(const uint4*)&Ss[nl][q0 + 384];
  const uint4 ghz = *(const uint4*)&Ss[nl][q0 + 512];
  const uint4 ghn = *(const uint4*)&Ss[nl][q0 + 640];
  const unsigned GIR[4] = {gir.x, gir.y, gir.z, gir.w};
  const unsigned GIZ[4] = {giz.x, giz.y, giz.z, giz.w};
  const unsigned GIN[4] = {gin.x, gin.y, gin.z, gin.w};
  const unsigned GHR[4] = {ghr.x, ghr.y, ghr.z, ghr.w};
  const unsigned GHZ[4] = {ghz.x, ghz.y, ghz.z, ghz.w};
  const unsigned GHN[4] = {ghn.x, ghn.y, ghn.z, ghn.w};
  float vb[8];
  float s1 = 0.0f, s2 = 0.0f;
#pragma unroll
  for (int j2 = 0; j2 < 4; ++j2) {
#pragma unroll
    for (int hl = 0; hl < 2; ++hl) {
      const int jj = j2 * 2 + hl;
      const unsigned sh = hl * 16;
      const float girv = bf2f((GIR[j2] >> sh) & 0xffffu);
      const float gizv = bf2f((GIZ[j2] >> sh) & 0xffffu);
      const float ginv = bf2f((GIN[j2] >> sh) & 0xffffu);
      const float ghrv = bf2f((GHR[j2] >> sh) & 0xffffu);
      const float ghzv = bf2f((GHZ[j2] >> sh) & 0xffffu);
      const float ghnv = bf2f((GHN[j2] >> sh) & 0xffffu);
      const float r = sigm(girv + ghrv);
      const float z = sigm(gizv + ghzv);
      const float nv = tanhf(ginv + r * ghnv);
      const float v = xv[jj] + (1.0f - z) * nv + z * xv[jj];
      vb[jj] = v; s1 += v; s2 += v * v;
    }
  }
  s1 += __shfl_xor(s1, 1); s2 += __shfl_xor(s2, 1);
  s1 += __shfl_xor(s1, 2); s2 += __shfl_xor(s2, 2);
  s1 += __shfl_xor(s1, 4); s2 += __shfl_xor(s2, 4);
  s1 += __shfl_xor(s1, 8); s2 += __shfl_xor(s2, 8);
  const float m = s1 * (1.0f / 128.0f);
  const float var = s2 * (1.0f / 128.0f) - m * m;
  const float rstd = rsqrtf(var + 1e-5f);
  float ov[8];
#pragma unroll
  for (int j = 0; j < 8; ++j)
    ov[j] = ln2g[q0 + j] * ((vb[j] - m) * rstd) + ln2b[q0 + j];
  *(float4*)(out + (size_t)gn * 128 + q0) = make_float4(ov[0], ov[1], ov[2], ov[3]);
  *(float4*)(out + (size_t)gn * 128 + q0 + 4) = make_float4(ov[4], ov[5], ov[6], ov[7]);
}

extern "C" void kernel_launch(void* const* d_in, const int* in_sizes, int n_in,
                              void* d_out, int out_size, void* d_ws, size_t ws_size,
                              hipStream_t stream) {
  const float* x         = (const float*)d_in[0];
  const float* edge_attr = (const float*)d_in[1];
  const float* pos       = (const float*)d_in[2];
  const float* W1        = (const float*)d_in[3];
  const float* b1        = (const float*)d_in[4];
  const float* ln1g      = (const float*)d_in[5];
  const float* ln1b      = (const float*)d_in[6];
  const float* W2        = (const float*)d_in[7];
  const float* b2        = (const float*)d_in[8];
  const float* Wih       = (const float*)d_in[9];
  const float* bih       = (const float*)d_in[10];
  const float* Whh       = (const float*)d_in[11];
  const float* bhh       = (const float*)d_in[12];
  const float* ln2g      = (const float*)d_in[13];
  const float* ln2b      = (const float*)d_in[14];
  const int*   ei        = (const int*)d_in[15];
  float* out = (float*)d_out;

  // ws layout (bytes)
  float*          sums  = (float*)d_ws;                                   // 25,600,000
  unsigned short* Pdb   = (unsigned short*)((char*)d_ws + 25600000);      // 12,800,000
  unsigned short* Psb   = (unsigned short*)((char*)d_ws + 38400000);      // 12,800,000
  unsigned short* frags = (unsigned short*)((char*)d_ws + 51200000);      //    303,104
  int*            deg   = (int*)((char*)d_ws + 51600000);                 //    200,000
  int*            cur   = (int*)((char*)d_ws + 51800000);                 //    200,000
  int*            offs  = (int*)((char*)d_ws + 52000000);                 //    200,000
  int*            bsum  = (int*)((char*)d_ws + 52200000);                 //        784
  int*            boff  = (int*)((char*)d_ws + 52204096);                 //        784
  int*            perm  = (int*)((char*)d_ws + 52300000);                 //  3,200,000
  unsigned short* W1ef = frags;               // 8 frags
  unsigned short* W2f  = frags + 8 * 512;     // 32 frags
  unsigned short* W1nf = frags + 40 * 512;    // 64 frags
  unsigned short* Wihf = frags + 104 * 512;   // 96 frags
  unsigned short* Whhf = frags + 200 * 512;   // 96 frags

  hipMemsetAsync(sums, 0, (size_t)NN * 128 * sizeof(float), stream);
  hipMemsetAsync(deg, 0, 2 * 200000, stream);   // deg + cur

  k0_prep<<<296, 64, 0, stream>>>(W1, W2, Wih, Whh, frags);
  k_hist<<<3125, 256, 0, stream>>>(ei, deg);
  kA_partial<<<196, 256, 0, stream>>>(deg, bsum);
  kB_scan<<<1, 256, 0, stream>>>(bsum, boff);
  kC_offs<<<196, 256, 0, stream>>>(deg, boff, offs);
  k_scatter<<<3125, 256, 0, stream>>>(ei, offs, cur, perm);
  k1_node_pre<<<3125, 256, 0, stream>>>(x, W1nf, Pdb, Psb);
  k2_edge<<<12500, 256, 0, stream>>>(Pdb, Psb, edge_attr, pos, ei, perm, W1ef, W2f,
                                     b1, ln1g, ln1b, sums);
  k3_gru<<<3125, 256, 0, stream>>>(x, sums, deg, Wihf, Whhf, bih, bhh, b2,
                                   ln2g, ln2b, out);
}

// Round 9
// 315.934 us; speedup vs baseline: 1.1745x; 1.0304x over previous
//
#include <hip/hip_runtime.h>
#include <math.h>

#define NN 50000
#define EE 800000

typedef __attribute__((ext_vector_type(8))) short bf16x8;
typedef __attribute__((ext_vector_type(4))) float f32x4;
typedef __attribute__((ext_vector_type(2))) float f32x2;

__device__ __forceinline__ float bf2f(unsigned int h16) {
  union { unsigned u; float f; } z; z.u = h16 << 16; return z.f;
}
__device__ __forceinline__ float uasf(unsigned u) {
  union { unsigned u; float f; } z; z.u = u; return z.f;
}
__device__ __forceinline__ unsigned cvtpk(float lo, float hi) {
  unsigned r;
  asm("v_cvt_pk_bf16_f32 %0, %1, %2" : "=v"(r) : "v"(lo), "v"(hi));
  return r;
}
__device__ __forceinline__ float sigm(float v) { return 1.0f / (1.0f + __expf(-v)); }

__device__ __forceinline__ bf16x8 pack8(float a0, float a1, float a2, float a3,
                                        float a4, float a5, float a6, float a7) {
  union { unsigned u[4]; bf16x8 v; } z;
  z.u[0] = cvtpk(a0, a1); z.u[1] = cvtpk(a2, a3);
  z.u[2] = cvtpk(a4, a5); z.u[3] = cvtpk(a6, a7);
  return z.v;
}

// ============ K0: pack all weights into bf16 MFMA A-fragments ============
__global__ __launch_bounds__(64) void k0_prep(const float* __restrict__ W1,
                                              const float* __restrict__ W2,
                                              const float* __restrict__ Wih,
                                              const float* __restrict__ Whh,
                                              unsigned short* __restrict__ frags) {
  const int f = blockIdx.x, l = threadIdx.x;
  const int c16 = l & 15, kg = l >> 4;
  float v[8];
  if (f < 8) {
    const int c = f * 16 + c16;
#pragma unroll
    for (int j = 0; j < 8; ++j) {
      const int k = kg * 8 + j;
      v[j] = (k < 20) ? W1[(256 + k) * 128 + c] : 0.0f;
    }
  } else if (f < 40) {
    const int lf = f - 8, ct = lf >> 2, ks = lf & 3, c = ct * 16 + c16;
#pragma unroll
    for (int j = 0; j < 8; ++j) { const int k = ks * 32 + kg * 8 + j; v[j] = W2[k * 128 + c]; }
  } else if (f < 104) {
    const int lf = f - 40, ct = lf >> 2, ks = lf & 3, c = ct * 16 + c16;
#pragma unroll
    for (int j = 0; j < 8; ++j) {
      const int k = ks * 32 + kg * 8 + j;
      v[j] = (c < 128) ? W1[k * 128 + c] : W1[(128 + k) * 128 + (c - 128)];
    }
  } else if (f < 200) {
    const int lf = f - 104, ct = lf >> 2, ks = lf & 3, c = ct * 16 + c16;
#pragma unroll
    for (int j = 0; j < 8; ++j) { const int k = ks * 32 + kg * 8 + j; v[j] = Wih[c * 128 + k]; }
  } else {
    const int lf = f - 200, ct = lf >> 2, ks = lf & 3, c = ct * 16 + c16;
#pragma unroll
    for (int j = 0; j < 8; ++j) { const int k = ks * 32 + kg * 8 + j; v[j] = Whh[c * 128 + k]; }
  }
  *(bf16x8*)(frags + (size_t)f * 512 + l * 8) =
      pack8(v[0], v[1], v[2], v[3], v[4], v[5], v[6], v[7]);
}

// ============ counting sort of edges by dst ============
__global__ __launch_bounds__(256) void k_hist(const int* __restrict__ ei,
                                              int* __restrict__ deg) {
  const int e = blockIdx.x * 256 + threadIdx.x;
  if (e < EE) atomicAdd(&deg[ei[EE + e]], 1);
}

__global__ __launch_bounds__(256) void kA_partial(const int* __restrict__ deg,
                                                  int* __restrict__ bsum) {
  const int i = blockIdx.x * 256 + threadIdx.x;
  int v = (i < NN) ? deg[i] : 0;
#pragma unroll
  for (int o = 32; o > 0; o >>= 1) v += __shfl_down(v, o);
  __shared__ int wsum[4];
  if ((threadIdx.x & 63) == 0) wsum[threadIdx.x >> 6] = v;
  __syncthreads();
  if (threadIdx.x == 0) bsum[blockIdx.x] = wsum[0] + wsum[1] + wsum[2] + wsum[3];
}

__global__ __launch_bounds__(256) void kB_scan(const int* __restrict__ bsum,
                                               int* __restrict__ boff) {
  __shared__ int s[256];
  const int t = threadIdx.x;
  const int orig = (t < 196) ? bsum[t] : 0;
  s[t] = orig;
  __syncthreads();
  for (int o = 1; o < 256; o <<= 1) {
    const int v = (t >= o) ? s[t - o] : 0;
    __syncthreads();
    s[t] += v;
    __syncthreads();
  }
  if (t < 196) boff[t] = s[t] - orig;
}

__global__ __launch_bounds__(256) void kC_offs(const int* __restrict__ deg,
                                               const int* __restrict__ boff,
                                               int* __restrict__ offs) {
  __shared__ int s[256];
  const int t = threadIdx.x, i = blockIdx.x * 256 + t;
  const int orig = (i < NN) ? deg[i] : 0;
  s[t] = orig;
  __syncthreads();
  for (int o = 1; o < 256; o <<= 1) {
    const int v = (t >= o) ? s[t - o] : 0;
    __syncthreads();
    s[t] += v;
    __syncthreads();
  }
  if (i < NN) offs[i] = boff[blockIdx.x] + s[t] - orig;
}

// PRE=false variant: permutation only
__global__ __launch_bounds__(256) void k_scatter(const int* __restrict__ ei,
                                                 const int* __restrict__ offs,
                                                 int* __restrict__ cur,
                                                 int* __restrict__ perm) {
  const int e = blockIdx.x * 256 + threadIdx.x;
  if (e < EE) {
    const int d = ei[EE + e];
    const int p = atomicAdd(&cur[d], 1);
    perm[offs[d] + p] = e;
  }
}

// PRE=true variant: materialize sorted dst/src + bf16-packed edge_attr fragments
__global__ __launch_bounds__(256) void k_prep_edges(const int* __restrict__ ei,
                                                    const float* __restrict__ edge_attr,
                                                    const int* __restrict__ offs,
                                                    int* __restrict__ cur,
                                                    int* __restrict__ dst_s,
                                                    int* __restrict__ src_s,
                                                    unsigned short* __restrict__ ea_s) {
  const int e = blockIdx.x * 256 + threadIdx.x;
  if (e >= EE) return;
  const int s = ei[e], d = ei[EE + e];
  const int p = offs[d] + atomicAdd(&cur[d], 1);
  dst_s[p] = d; src_s[p] = s;
  const float* ep = edge_attr + (size_t)e * 16;
  const float4 u  = *(const float4*)ep,       v  = *(const float4*)(ep + 4);
  const float4 u2 = *(const float4*)(ep + 8), v2 = *(const float4*)(ep + 12);
  unsigned short* fp = ea_s + (size_t)p * 16;
  *(bf16x8*)(fp)     = pack8(u.x, u.y, u.z, u.w, v.x, v.y, v.z, v.w);
  *(bf16x8*)(fp + 8) = pack8(u2.x, u2.y, u2.z, u2.w, v2.x, v2.y, v2.z, v2.w);
}

// ============ K1: Pd = x@W1_dst, Ps = x@W1_src — frag-grouped, split arrays ============
__global__ __launch_bounds__(256) void k1_node_pre(const float* __restrict__ x,
                                                   const unsigned short* __restrict__ W1nf,
                                                   unsigned short* __restrict__ Pd,
                                                   unsigned short* __restrict__ Ps) {
  const int t = threadIdx.x, lane = t & 63, w = t >> 6;
  const int kg = lane >> 4, li = lane & 15;
  const int node = blockIdx.x * 16 + li;   // 3125*16 = 50000 exact
  const f32x4 zf = {0.0f, 0.0f, 0.0f, 0.0f};
  f32x4 acc[4] = {zf, zf, zf, zf};
#pragma unroll
  for (int ks = 0; ks < 4; ++ks) {
    const float* xp = x + (size_t)node * 128 + ks * 32 + kg * 8;
    const float4 u = *(const float4*)xp, v = *(const float4*)(xp + 4);
    const bf16x8 xb = pack8(u.x, u.y, u.z, u.w, v.x, v.y, v.z, v.w);
#pragma unroll
    for (int i = 0; i < 4; ++i) {
      const int ct = w * 4 + i;
      const bf16x8 af = *(const bf16x8*)(W1nf + (size_t)(ct * 4 + ks) * 512 + lane * 8);
      acc[i] = __builtin_amdgcn_mfma_f32_16x16x32_bf16(af, xb, acc[i], 0, 0, 0);
    }
  }
#pragma unroll
  for (int i = 0; i < 4; ++i) {
    const int C = w * 4 + i;                         // 0..15
    unsigned short* base = (C < 8) ? Pd : Ps;
    const int off = kg * 32 + (C & 7) * 4;
    *(uint2*)(base + (size_t)node * 128 + off) =
        make_uint2(cvtpk(acc[i][0], acc[i][1]), cvtpk(acc[i][2], acc[i][3]));
  }
}

// ============ K2: fused edge kernel ============
template <bool PRE>
__global__ __launch_bounds__(256) void k2_edge(const unsigned short* __restrict__ Pd,
                                               const unsigned short* __restrict__ Ps,
                                               const float* __restrict__ edge_attr,
                                               const float* __restrict__ pos,
                                               const int* __restrict__ ei,
                                               const int* __restrict__ perm,
                                               const int* __restrict__ dst_s,
                                               const int* __restrict__ src_s,
                                               const unsigned short* __restrict__ ea_s,
                                               const unsigned short* __restrict__ W1ef,
                                               const unsigned short* __restrict__ W2f,
                                               const float* __restrict__ b1,
                                               const float* __restrict__ ln1g,
                                               const float* __restrict__ ln1b,
                                               float* __restrict__ sums) {
  __shared__ __align__(16) unsigned short htile[64][136];  // h (bf16), then msg in place
  __shared__ __align__(16) float4 relv[64];                // !PRE only
  __shared__ int dsts[64], srcs[64], eids[64];             // eids !PRE only
  __shared__ int runStart[65];
  __shared__ int runCnt;
  __shared__ __align__(16) float b1s[128];
  __shared__ __align__(16) float g1s[128];
  __shared__ __align__(16) float bb1s[128];

  const int t = threadIdx.x, lane = t & 63, w = t >> 6;
  const int kg = lane >> 4, li = lane & 15;
  const int e0 = blockIdx.x * 64;   // 12500*64 = 800000 exact
  const int el = w * 16 + li;       // this lane's edge row

  if (t < 128) { b1s[t] = b1[t]; g1s[t] = ln1g[t]; bb1s[t] = ln1b[t]; }
  if (PRE) {
    if (t < 64) { dsts[t] = dst_s[e0 + t]; srcs[t] = src_s[e0 + t]; }
  } else {
    if (t < 64) {
      const int e = perm[e0 + t];
      eids[t] = e;
      const int s = ei[e], d = ei[EE + e];
      srcs[t] = s; dsts[t] = d;
      const float rx = (pos[3 * s + 0] - pos[3 * d + 0]) * 0.2f;
      const float ry = (pos[3 * s + 1] - pos[3 * d + 1]) * 0.2f;
      const float rz = (pos[3 * s + 2] - pos[3 * d + 2]) * 0.2f;
      relv[t] = make_float4(rx, ry, rz, rx * rx + ry * ry + rz * rz);
    }
  }
  __syncthreads();   // barrier 1

  // ---- run table (wave 0 only): ballot over dst-change flags ----
  if (w == 0) {
    const bool flag = (lane == 0) || (dsts[lane] != dsts[lane - 1]);
    const unsigned long long mask = __ballot(flag);
    const int rid = __popcll(mask & ((1ull << lane) - 1ull));
    if (flag) runStart[rid] = lane;
    if (lane == 63) {
      const int nr = __popcll(mask);
      runCnt = nr;
      runStart[nr] = 64;
    }
  }

  // ---- split-P fragment gathers: 64B/lane contiguous, fully used ----
  const int dn = dsts[el], sn = srcs[el];
  const uint4* pdp = (const uint4*)(Pd + (size_t)dn * 128 + kg * 32);
  const uint4* psp = (const uint4*)(Ps + (size_t)sn * 128 + kg * 32);
  uint4 PV[4] = {pdp[0], pdp[1], pdp[2], pdp[3]};
  uint4 SV[4] = {psp[0], psp[1], psp[2], psp[3]};

  // ---- A1 fragment ----
  bf16x8 bfrag;
  if (PRE) {
    if (kg < 2) {
      bfrag = *(const bf16x8*)(ea_s + (size_t)(e0 + el) * 16 + kg * 8);
    } else if (kg == 2) {
      const float rx = (pos[3 * sn + 0] - pos[3 * dn + 0]) * 0.2f;
      const float ry = (pos[3 * sn + 1] - pos[3 * dn + 1]) * 0.2f;
      const float rz = (pos[3 * sn + 2] - pos[3 * dn + 2]) * 0.2f;
      bfrag = pack8(rx, ry, rz, rx * rx + ry * ry + rz * rz, 0.f, 0.f, 0.f, 0.f);
    } else {
      bfrag = pack8(0.f, 0.f, 0.f, 0.f, 0.f, 0.f, 0.f, 0.f);
    }
  } else {
    if (kg < 2) {
      const float* ep = edge_attr + (size_t)eids[el] * 16 + kg * 8;
      const float4 u = *(const float4*)ep, v = *(const float4*)(ep + 4);
      bfrag = pack8(u.x, u.y, u.z, u.w, v.x, v.y, v.z, v.w);
    } else if (kg == 2) {
      const float4 rv = relv[el];
      bfrag = pack8(rv.x, rv.y, rv.z, rv.w, 0.f, 0.f, 0.f, 0.f);
    } else {
      bfrag = pack8(0.f, 0.f, 0.f, 0.f, 0.f, 0.f, 0.f, 0.f);
    }
  }

  // ---- A1: acc = (ea|geom) @ W1[256:276] + b1 (b1 as C operand) ----
  f32x4 acc[8];
#pragma unroll
  for (int cf = 0; cf < 8; ++cf) {
    const f32x4 bC = *(const f32x4*)&b1s[cf * 16 + kg * 4];
    const bf16x8 af = *(const bf16x8*)(W1ef + (size_t)cf * 512 + lane * 8);
    acc[cf] = __builtin_amdgcn_mfma_f32_16x16x32_bf16(af, bfrag, bC, 0, 0, 0);
  }

  // ---- A2: acc += Pd + Ps ; LN stats on f32x2 pairs (pk math) ----
  f32x2 sv1 = {0.0f, 0.0f}, sv2 = {0.0f, 0.0f};
#pragma unroll
  for (int q = 0; q < 4; ++q) {
    const unsigned pdx[4] = {PV[q].x, PV[q].y, PV[q].z, PV[q].w};
    const unsigned psx[4] = {SV[q].x, SV[q].y, SV[q].z, SV[q].w};
#pragma unroll
    for (int h2 = 0; h2 < 4; ++h2) {
      const int cf = 2 * q + (h2 >> 1);
      const int j0 = (h2 & 1) * 2;
      f32x2 pd2; pd2[0] = uasf(pdx[h2] << 16); pd2[1] = uasf(pdx[h2] & 0xffff0000u);
      f32x2 ps2; ps2[0] = uasf(psx[h2] << 16); ps2[1] = uasf(psx[h2] & 0xffff0000u);
      f32x2 av;  av[0] = acc[cf][j0]; av[1] = acc[cf][j0 + 1];
      av = av + pd2 + ps2;
      acc[cf][j0] = av[0]; acc[cf][j0 + 1] = av[1];
      sv1 += av;
      sv2 += av * av;
    }
  }
  float s1 = sv1[0] + sv1[1], s2 = sv2[0] + sv2[1];
  s1 += __shfl_xor(s1, 16); s2 += __shfl_xor(s2, 16);
  s1 += __shfl_xor(s1, 32); s2 += __shfl_xor(s2, 32);
  const float m = s1 * (1.0f / 128.0f);
  const float var = s2 * (1.0f / 128.0f) - m * m;
  const float rstd = rsqrtf(var + 1e-5f);
  const f32x2 mneg = {-m, -m};
  const f32x2 rr2 = {rstd, rstd};
#pragma unroll
  for (int cf = 0; cf < 8; ++cf) {
    unsigned ow[2];
#pragma unroll
    for (int p2 = 0; p2 < 2; ++p2) {
      const f32x2 g2 = *(const f32x2*)&g1s[cf * 16 + kg * 4 + p2 * 2];
      const f32x2 be = *(const f32x2*)&bb1s[cf * 16 + kg * 4 + p2 * 2];
      f32x2 xv; xv[0] = acc[cf][p2 * 2]; xv[1] = acc[cf][p2 * 2 + 1];
      f32x2 y = (xv + mneg) * rr2 * g2 + be;
      float y0 = y[0], y1 = y[1];
      y0 *= sigm(y0); y1 *= sigm(y1);
      ow[p2] = cvtpk(y0, y1);
    }
    *(uint2*)&htile[el][cf * 16 + kg * 4] = make_uint2(ow[0], ow[1]);
  }

  // intra-wave LDS ordering (wave's writes land before its cross-lane reads)
  asm volatile("s_waitcnt lgkmcnt(0)" ::: "memory");
  __builtin_amdgcn_sched_barrier(0);

  // ---- B: msg^T = W2^T x h (own rows only), write msg back in place ----
  {
    bf16x8 hfr[4];
#pragma unroll
    for (int ks = 0; ks < 4; ++ks)
      hfr[ks] = *(const bf16x8*)&htile[el][ks * 32 + kg * 8];

    const f32x4 zf = {0.0f, 0.0f, 0.0f, 0.0f};
    f32x4 macc[8];
#pragma unroll
    for (int cf = 0; cf < 8; ++cf) macc[cf] = zf;
#pragma unroll
    for (int ks = 0; ks < 4; ++ks) {
#pragma unroll
      for (int cf = 0; cf < 8; ++cf) {
        const bf16x8 wf = *(const bf16x8*)(W2f + (size_t)((cf << 2) | ks) * 512 + lane * 8);
        macc[cf] = __builtin_amdgcn_mfma_f32_16x16x32_bf16(wf, hfr[ks], macc[cf], 0, 0, 0);
      }
    }
#pragma unroll
    for (int cf = 0; cf < 8; ++cf) {
      *(uint2*)&htile[el][cf * 16 + kg * 4] =
          make_uint2(cvtpk(macc[cf][0], macc[cf][1]), cvtpk(macc[cf][2], macc[cf][3]));
    }
  }
  __syncthreads();   // barrier 2

  // ---- C: run-table segmented reduce on column pairs (b32 + pk adds) ----
  {
    const int nruns = runCnt;
    const int ntask = nruns << 6;            // nruns * 64 col-pairs
    for (int base = w * 64; base < ntask; base += 256) {
      const int run = base >> 6;             // wave-uniform
      const int cp = lane;                   // col pair 0..63
      const int s    = __builtin_amdgcn_readfirstlane(runStart[run]);
      const int epos = __builtin_amdgcn_readfirstlane(runStart[run + 1]);
      const int dd   = __builtin_amdgcn_readfirstlane(dsts[s]);
      f32x2 racc = {0.0f, 0.0f};
      for (int e = s; e < epos; ++e) {
        const unsigned vv = *(const unsigned*)&htile[e][cp * 2];
        f32x2 f; f[0] = uasf(vv << 16); f[1] = uasf(vv & 0xffff0000u);
        racc += f;
      }
      atomicAdd(sums + (size_t)dd * 128 + cp * 2,     racc[0]);
      atomicAdd(sums + (size_t)dd * 128 + cp * 2 + 1, racc[1]);
    }
  }
}

// ============ K3: GRU + LN2 (MFMA), 16 nodes per block ============
__global__ __launch_bounds__(256) void k3_gru(const float* __restrict__ x,
                                              const float* __restrict__ sums,
                                              const int* __restrict__ deg,
                                              const unsigned short* __restrict__ Wihf,
                                              const unsigned short* __restrict__ Whhf,
                                              const float* __restrict__ bih,
                                              const float* __restrict__ bhh,
                                              const float* __restrict__ b2,
                                              const float* __restrict__ ln2g,
                                              const float* __restrict__ ln2b,
                                              float* __restrict__ out) {
  __shared__ unsigned short aggb[16][136];   // agg bf16
  __shared__ unsigned short Ss[16][776];     // [gi(384) | gh(384)] bf16
  const int t = threadIdx.x, lane = t & 63, w = t >> 6;
  const int kg = lane >> 4, li = lane & 15;
  const int n0 = blockIdx.x * 16;   // 3125*16 = 50000 exact

  // stage agg = sums/max(deg,1) + (deg>0)*b2
  {
    const int nl = t >> 4, c0 = (t & 15) * 8;
    const int gn = n0 + nl;
    const int dc = deg[gn];
    const float inv = 1.0f / fmaxf((float)dc, 1.0f);
    const float bsc = (dc > 0) ? 1.0f : 0.0f;
    const float* sp = sums + (size_t)gn * 128 + c0;
    const float4 u = *(const float4*)sp, v = *(const float4*)(sp + 4);
    const float4 bu = *(const float4*)(b2 + c0), bv = *(const float4*)(b2 + c0 + 4);
    const unsigned o0 = cvtpk(u.x * inv + bsc * bu.x, u.y * inv + bsc * bu.y);
    const unsigned o1 = cvtpk(u.z * inv + bsc * bu.z, u.w * inv + bsc * bu.w);
    const unsigned o2 = cvtpk(v.x * inv + bsc * bv.x, v.y * inv + bsc * bv.y);
    const unsigned o3 = cvtpk(v.z * inv + bsc * bv.z, v.w * inv + bsc * bv.w);
    *(uint4*)&aggb[nl][c0] = make_uint4(o0, o1, o2, o3);
  }
  __syncthreads();

  // waves 0-1: gi = agg@Wih^T ; waves 2-3: gh = x@Whh^T
  const int isH = w >> 1;
  const int ctbase = (w & 1) * 12;
  const unsigned short* Wf = isH ? Whhf : Wihf;
  const float* bias = isH ? bhh : bih;
  const f32x4 zf = {0.0f, 0.0f, 0.0f, 0.0f};
  f32x4 acc[12];
#pragma unroll
  for (int i = 0; i < 12; ++i) acc[i] = zf;
#pragma unroll
  for (int ks = 0; ks < 4; ++ks) {
    bf16x8 bfrag;
    if (isH) {
      const float* xp = x + (size_t)(n0 + li) * 128 + ks * 32 + kg * 8;
      const float4 u = *(const float4*)xp, v = *(const float4*)(xp + 4);
      bfrag = pack8(u.x, u.y, u.z, u.w, v.x, v.y, v.z, v.w);
    } else {
      bfrag = *(const bf16x8*)&aggb[li][ks * 32 + kg * 8];
    }
#pragma unroll
    for (int i = 0; i < 12; ++i) {
      const int ct = ctbase + i;
      const bf16x8 af = *(const bf16x8*)(Wf + (size_t)(ct * 4 + ks) * 512 + lane * 8);
      acc[i] = __builtin_amdgcn_mfma_f32_16x16x32_bf16(af, bfrag, acc[i], 0, 0, 0);
    }
  }
#pragma unroll
  for (int i = 0; i < 12; ++i) {
    const int ocol = (ctbase + i) * 16 + kg * 4;
    const float4 bb = *(const float4*)(bias + ocol);
    const int col = isH * 384 + ocol;
    const unsigned lo = cvtpk(acc[i][0] + bb.x, acc[i][1] + bb.y);
    const unsigned hi = cvtpk(acc[i][2] + bb.z, acc[i][3] + bb.w);
    *(uint2*)&Ss[li][col] = make_uint2(lo, hi);
  }
  __syncthreads();

  // gates + residual + LN2
  const int nl = t >> 4, q0 = (t & 15) * 8;
  const int gn = n0 + nl;
  float xv[8];
  *(float4*)&xv[0] = *(const float4*)(x + (size_t)gn * 128 + q0);
  *(float4*)&xv[4] = *(const float4*)(x + (size_t)gn * 128 + q0 + 4);
  const uint4 gir = *(const uint4*)&Ss[nl][q0];
  const uint4 giz = *(const uint4*)&Ss[nl][q0 + 128];
  const uint4 gin = *(const uint4*)&Ss[nl][q0 + 256];
  const uint4 ghr = *(const uint4*)&Ss[nl][q0 + 384];
  const uint4 ghz = *(const uint4*)&Ss[nl][q0 + 512];
  const uint4 ghn = *(const uint4*)&Ss[nl][q0 + 640];
  const unsigned GIR[4] = {gir.x, gir.y, gir.z, gir.w};
  const unsigned GIZ[4] = {giz.x, giz.y, giz.z, giz.w};
  const unsigned GIN[4] = {gin.x, gin.y, gin.z, gin.w};
  const unsigned GHR[4] = {ghr.x, ghr.y, ghr.z, ghr.w};
  const unsigned GHZ[4] = {ghz.x, ghz.y, ghz.z, ghz.w};
  const unsigned GHN[4] = {ghn.x, ghn.y, ghn.z, ghn.w};
  float vb[8];
  float s1 = 0.0f, s2 = 0.0f;
#pragma unroll
  for (int j2 = 0; j2 < 4; ++j2) {
#pragma unroll
    for (int hl = 0; hl < 2; ++hl) {
      const int jj = j2 * 2 + hl;
      const unsigned sh = hl * 16;
      const float girv = bf2f((GIR[j2] >> sh) & 0xffffu);
      const float gizv = bf2f((GIZ[j2] >> sh) & 0xffffu);
      const float ginv = bf2f((GIN[j2] >> sh) & 0xffffu);
      const float ghrv = bf2f((GHR[j2] >> sh) & 0xffffu);
      const float ghzv = bf2f((GHZ[j2] >> sh) & 0xffffu);
      const float ghnv = bf2f((GHN[j2] >> sh) & 0xffffu);
      const float r = sigm(girv + ghrv);
      const float z = sigm(gizv + ghzv);
      const float nv = tanhf(ginv + r * ghnv);
      const float v = xv[jj] + (1.0f - z) * nv + z * xv[jj];
      vb[jj] = v; s1 += v; s2 += v * v;
    }
  }
  s1 += __shfl_xor(s1, 1); s2 += __shfl_xor(s2, 1);
  s1 += __shfl_xor(s1, 2); s2 += __shfl_xor(s2, 2);
  s1 += __shfl_xor(s1, 4); s2 += __shfl_xor(s2, 4);
  s1 += __shfl_xor(s1, 8); s2 += __shfl_xor(s2, 8);
  const float m = s1 * (1.0f / 128.0f);
  const float var = s2 * (1.0f / 128.0f) - m * m;
  const float rstd = rsqrtf(var + 1e-5f);
  float ov[8];
#pragma unroll
  for (int j = 0; j < 8; ++j)
    ov[j] = ln2g[q0 + j] * ((vb[j] - m) * rstd) + ln2b[q0 + j];
  *(float4*)(out + (size_t)gn * 128 + q0) = make_float4(ov[0], ov[1], ov[2], ov[3]);
  *(float4*)(out + (size_t)gn * 128 + q0 + 4) = make_float4(ov[4], ov[5], ov[6], ov[7]);
}

extern "C" void kernel_launch(void* const* d_in, const int* in_sizes, int n_in,
                              void* d_out, int out_size, void* d_ws, size_t ws_size,
                              hipStream_t stream) {
  const float* x         = (const float*)d_in[0];
  const float* edge_attr = (const float*)d_in[1];
  const float* pos       = (const float*)d_in[2];
  const float* W1        = (const float*)d_in[3];
  const float* b1        = (const float*)d_in[4];
  const float* ln1g      = (const float*)d_in[5];
  const float* ln1b      = (const float*)d_in[6];
  const float* W2        = (const float*)d_in[7];
  const float* b2        = (const float*)d_in[8];
  const float* Wih       = (const float*)d_in[9];
  const float* bih       = (const float*)d_in[10];
  const float* Whh       = (const float*)d_in[11];
  const float* bhh       = (const float*)d_in[12];
  const float* ln2g      = (const float*)d_in[13];
  const float* ln2b      = (const float*)d_in[14];
  const int*   ei        = (const int*)d_in[15];
  float* out = (float*)d_out;

  // ws layout (bytes)
  float*          sums  = (float*)d_ws;                                   // 25,600,000
  unsigned short* Pdb   = (unsigned short*)((char*)d_ws + 25600000);      // 12,800,000
  unsigned short* Psb   = (unsigned short*)((char*)d_ws + 38400000);      // 12,800,000
  unsigned short* frags = (unsigned short*)((char*)d_ws + 51200000);      //    303,104
  int*            deg   = (int*)((char*)d_ws + 51600000);                 //    200,000
  int*            cur   = (int*)((char*)d_ws + 51800000);                 //    200,000
  int*            offs  = (int*)((char*)d_ws + 52000000);                 //    200,000
  int*            bsum  = (int*)((char*)d_ws + 52200000);                 //        784
  int*            boff  = (int*)((char*)d_ws + 52204096);                 //        784
  // tail region, two mutually-exclusive layouts:
  int*            perm  = (int*)((char*)d_ws + 52300000);                 //  3,200,000 (fallback)
  int*            dst_s = (int*)((char*)d_ws + 52300000);                 //  3,200,000 (PRE)
  int*            src_s = (int*)((char*)d_ws + 55500000);                 //  3,200,000 (PRE)
  unsigned short* ea_s  = (unsigned short*)((char*)d_ws + 58700000);      // 25,600,000 (PRE)
  unsigned short* W1ef = frags;               // 8 frags
  unsigned short* W2f  = frags + 8 * 512;     // 32 frags
  unsigned short* W1nf = frags + 40 * 512;    // 64 frags
  unsigned short* Wihf = frags + 104 * 512;   // 96 frags
  unsigned short* Whhf = frags + 200 * 512;   // 96 frags

  const bool pre = (ws_size >= (size_t)84300000);

  hipMemsetAsync(sums, 0, (size_t)NN * 128 * sizeof(float), stream);
  hipMemsetAsync(deg, 0, 2 * 200000, stream);   // deg + cur

  k0_prep<<<296, 64, 0, stream>>>(W1, W2, Wih, Whh, frags);
  k_hist<<<3125, 256, 0, stream>>>(ei, deg);
  kA_partial<<<196, 256, 0, stream>>>(deg, bsum);
  kB_scan<<<1, 256, 0, stream>>>(bsum, boff);
  kC_offs<<<196, 256, 0, stream>>>(deg, boff, offs);
  k1_node_pre<<<3125, 256, 0, stream>>>(x, W1nf, Pdb, Psb);
  if (pre) {
    k_prep_edges<<<3125, 256, 0, stream>>>(ei, edge_attr, offs, cur,
                                           dst_s, src_s, ea_s);
    k2_edge<true><<<12500, 256, 0, stream>>>(Pdb, Psb, edge_attr, pos, ei,
                                             nullptr, dst_s, src_s, ea_s,
                                             W1ef, W2f, b1, ln1g, ln1b, sums);
  } else {
    k_scatter<<<3125, 256, 0, stream>>>(ei, offs, cur, perm);
    k2_edge<false><<<12500, 256, 0, stream>>>(Pdb, Psb, edge_attr, pos, ei,
                                              perm, nullptr, nullptr, nullptr,
                                              W1ef, W2f, b1, ln1g, ln1b, sums);
  }
  k3_gru<<<3125, 256, 0, stream>>>(x, sums, deg, Wihf, Whhf, bih, bhh, b2,
                                   ln2g, ln2b, out);
}